// Round 8
// baseline (453.748 us; speedup 1.0000x reference)
//
#include <hip/hip_runtime.h>
#include <hip/hip_bf16.h>
#include <stdint.h>

typedef __hip_bfloat16 bf16;
using frag_ab = __attribute__((ext_vector_type(8))) short;
using frag_cd = __attribute__((ext_vector_type(4))) float;

static __device__ __forceinline__ float hsig(float x){
    return fminf(fmaxf((x + 3.0f) * (1.0f/6.0f), 0.0f), 1.0f);
}
static __device__ __forceinline__ float bfu(unsigned short u){
    union{ unsigned int i; float f; } c; c.i = ((unsigned int)u) << 16; return c.f;
}
// float -> bf16 bits, round-to-nearest-even (matches __float2bfloat16 for finite values)
static __device__ __forceinline__ unsigned int bf16r(float f){
    union{ float f; unsigned int u; } c; c.f = f;
    return (c.u + 0x7fffu + ((c.u >> 16) & 1u)) >> 16;
}
static inline int ceildiv(int a, int b){ return (a + b - 1) / b; }

// ================= descriptor structs (passed by value in kernel args) =================
struct VD { const float* w; bf16* bw; int Opad, Ovalid, blk0; };
struct VD4 { VD d[4]; };
struct XD { const float* X; bf16* O; int HW, Ptot, blk0; };
struct XD3 { XD d[3]; };
struct FD {
    const bf16* X16; const float* OM; const bf16* Bw;
    float* C; const float* bias; float* PART;
    int Mtot, ldc, Nvalid, sigfrom;
    int Ho, Wo, Hi, Wi, Wm, HmWm, stride, osub, blk0, pad;
};
struct FD7 { FD d[7]; int n; };
struct SD { const float* part; const float* gamma; const float* beta;
            float* stats; float* gapn; int nblk, HW; };
struct SD7 { SD d[7]; };
struct WD { const float* Fs; float* partw; int Hh, Wh, Hm, Wm; };
struct WD2 { WD d[2]; };
struct AD { const float* gapn; const float* partw; const float* statsH; float invHW; int nbr; };
struct AD3 { AD d[3]; };
struct CD { const float* f0; const float* f1; const float* Fs;
            const float* stats; const float* abr; const float* dyc; float* outp;
            int H, W, nbr, Hh, Wh, slotH, blk0; };
struct CD3 { CD d[3]; };

// ================= batched weight conversion: w[O][256][3][3] -> bw[Opad][2304], K=k*256+c ======
__global__ __launch_bounds__(256) void k_convwB(VD4 P){
    int bx = blockIdx.x, j = 0;
    #pragma unroll
    for (int i = 1; i < 4; ++i) if (bx >= P.d[i].blk0) j = i;
    const float* w = P.d[j].w; bf16* bw = P.d[j].bw;
    int Opad = P.d[j].Opad, Ovalid = P.d[j].Ovalid;
    int i = (bx - P.d[j].blk0)*256 + threadIdx.x;
    if (i >= Opad*2304) return;
    int o = i / 2304, r = i - o*2304;
    int k = r >> 8, c = r & 255;
    float v = 0.f;
    if (o < Ovalid) v = w[((size_t)(o*256 + c))*9 + k];
    bw[i] = __float2bfloat16(v);
}

// ================= batched X fp32 NCHW -> bf16 NHWC =================
__global__ __launch_bounds__(256) void k_xconvB(XD3 P){
    __shared__ bf16 T[64][264];      // stride 264: rows 16B-aligned at multiples of 8 elems
    int bx = blockIdx.x, j = 0;
    #pragma unroll
    for (int i = 1; i < 3; ++i) if (bx >= P.d[i].blk0) j = i;
    const float* X = P.d[j].X; bf16* O = P.d[j].O;
    int HW = P.d[j].HW, Ptot = P.d[j].Ptot;
    int t = threadIdx.x;
    int pbase = (bx - P.d[j].blk0)*64;
    int px = t & 63, cg = t >> 6;
    int p = pbase + px;
    if (p < Ptot){
        int b = p / HW, rem = p - b*HW;
        const float* xb = X + (size_t)b*256*HW + rem;
        for (int c = cg; c < 256; c += 4)
            T[px][c] = __float2bfloat16(xb[(size_t)c*HW]);
    }
    __syncthreads();
    for (int jj = 0; jj < 8; ++jj){
        int chunk = jj*256 + t;
        int opx = chunk >> 5, c8 = (chunk & 31) << 3;
        if (pbase + opx < Ptot){
            uint4 u = *(const uint4*)&T[opx][c8];     // aligned LDS read, no reg address-of
            *(uint4*)&O[((size_t)(pbase + opx))*256 + c8] = u;
        }
    }
}

// ================= batched fused deformable-gather + NT GEMM (+GN partials) =================
// Block: 512 thr (8 waves, wave grid 2x4). Tile: 64 px x BN (BN = NR*64) — full N in one block.
// All per-thread state in named scalars/vectors — NO address-taken register arrays (spill fix).
template<int NR, bool DOSTATS>
__global__ __launch_bounds__(512) void k_fusedB(FD7 P){
    constexpr int BN  = NR*64;
    constexpr int SMEMB = (64*64 + BN*64)*2 + 9*64*32;
    __shared__ __align__(16) char smem[SMEMB];
    bf16* sA = (bf16*)smem;
    bf16* sB = sA + 64*64;
    int*  smi = (int*)(smem + (size_t)(64*64 + BN*64)*2);
    float* smw = (float*)(smi + 9*64*4);
    float* sP = (float*)smem;

    int bx = blockIdx.x, j = 0;
    #pragma unroll
    for (int i = 1; i < 7; ++i) if (i < P.n && bx >= P.d[i].blk0) j = i;
    const bf16* __restrict__ X16 = P.d[j].X16;
    const float* __restrict__ OM = P.d[j].OM;
    const bf16* __restrict__ Bw  = P.d[j].Bw;
    float* __restrict__ C        = P.d[j].C;
    const float* __restrict__ bias = P.d[j].bias;
    float* __restrict__ PART     = P.d[j].PART;
    const int Mtot = P.d[j].Mtot, ldc = P.d[j].ldc, Nvalid = P.d[j].Nvalid, sigfrom = P.d[j].sigfrom;
    const int Ho = P.d[j].Ho, Wo = P.d[j].Wo, Hi = P.d[j].Hi, Wi = P.d[j].Wi;
    const int Wm = P.d[j].Wm, HmWm = P.d[j].HmWm, stride = P.d[j].stride, osub = P.d[j].osub;
    const int bl = bx - P.d[j].blk0;

    const int t = threadIdx.x;
    const int m0 = bl * 64;
    const int HoWo = Ho * Wo;
    const int HiWi = Hi * Wi;
    const int px = t & 63;
    const int cg = t >> 6;          // 0..7: channel chunk of 8 for A; also wave id

    // ---- meta: per (pixel, tap) 4 corner bases (x256 elems) + 4 weights ----
    for (int i = t; i < 576; i += 512){
        int p_ = i & 63, k = i >> 6;
        int p = m0 + p_;
        bool pv = p < Mtot;
        int pp = pv ? p : 0;
        int b = pp / HoWo; int r = pp - b*HoWo; int y = r / Wo; int x = r - y*Wo;
        float offy = 0.f, offx = 0.f, mk = 1.f;
        if (OM){
            size_t ob = ((size_t)b*HmWm + (size_t)(y*osub)*Wm + (size_t)(x*osub)) * 32;
            offy = OM[ob + 2*k]; offx = OM[ob + 2*k + 1]; mk = OM[ob + 18 + k];
        }
        if (!pv) mk = 0.f;
        int kh = k/3, kw = k - kh*3;
        float py = (float)(y*stride - 1 + kh) + offy;
        float pxf = (float)(x*stride - 1 + kw) + offx;
        float y0f = floorf(py), x0f = floorf(pxf);
        float ly = py - y0f, lx = pxf - x0f;
        int y0 = (int)y0f, x0 = (int)x0f;
        int y1 = y0 + 1, x1 = x0 + 1;
        float vy0 = (y0 >= 0 && y0 < Hi) ? 1.f : 0.f;
        float vy1 = (y1 >= 0 && y1 < Hi) ? 1.f : 0.f;
        float vx0 = (x0 >= 0 && x0 < Wi) ? 1.f : 0.f;
        float vx1 = (x1 >= 0 && x1 < Wi) ? 1.f : 0.f;
        int y0c = min(max(y0,0),Hi-1), y1c = min(max(y1,0),Hi-1);
        int x0c = min(max(x0,0),Wi-1), x1c = min(max(x1,0),Wi-1);
        int base = b*HiWi;
        smi[(k*64+p_)*4+0] = (base + y0c*Wi + x0c) << 8;
        smi[(k*64+p_)*4+1] = (base + y0c*Wi + x1c) << 8;
        smi[(k*64+p_)*4+2] = (base + y1c*Wi + x0c) << 8;
        smi[(k*64+p_)*4+3] = (base + y1c*Wi + x1c) << 8;
        smw[(k*64+p_)*4+0] = (1.f-ly)*(1.f-lx)*mk*vy0*vx0;
        smw[(k*64+p_)*4+1] = (1.f-ly)*lx*mk*vy0*vx1;
        smw[(k*64+p_)*4+2] = ly*(1.f-lx)*mk*vy1*vx0;
        smw[(k*64+p_)*4+3] = ly*lx*mk*vy1*vx1;
    }
    __syncthreads();

    frag_cd acc[2][NR];
    frag_cd zero = {0.f,0.f,0.f,0.f};
    #pragma unroll
    for (int i = 0; i < 2; ++i)
        #pragma unroll
        for (int jj = 0; jj < NR; ++jj) acc[i][jj] = zero;

    const int l = t & 63;
    const int wr = cg >> 2, wc = cg & 3;     // 2x4 wave grid
    const int lr = l & 15, lq = l >> 4;
    const int lk8 = lq * 8;

    uint4 bA[NR];
    uint4 xA0, xA1, xA2, xA3;
    float4 cw;

    auto load_g = [&](int kt){
        int k = kt >> 2;
        int cb = (kt & 3) << 6;
        int4 ci = *(const int4*)&smi[(k*64+px)*4];
        cw = *(const float4*)&smw[(k*64+px)*4];
        int coff = cb + cg*8;
        xA0 = *(const uint4*)&X16[ci.x + coff];
        xA1 = *(const uint4*)&X16[ci.y + coff];
        xA2 = *(const uint4*)&X16[ci.z + coff];
        xA3 = *(const uint4*)&X16[ci.w + coff];
        #pragma unroll
        for (int i = 0; i < NR; ++i){
            int s = i*512 + t;
            int row = s >> 3, c8 = (s & 7) << 3;
            bA[i] = *(const uint4*)&Bw[(size_t)row*2304 + kt*64 + c8];
        }
    };

    // bilinear mix of one packed pair (2 bf16 per uint), pure bit-ops — no address-of
    auto mix = [&](unsigned int a, unsigned int b, unsigned int c, unsigned int d)->unsigned int{
        float lo = cw.x*bfu((unsigned short)(a & 0xffffu)) + cw.y*bfu((unsigned short)(b & 0xffffu))
                 + cw.z*bfu((unsigned short)(c & 0xffffu)) + cw.w*bfu((unsigned short)(d & 0xffffu));
        float hi = cw.x*bfu((unsigned short)(a >> 16)) + cw.y*bfu((unsigned short)(b >> 16))
                 + cw.z*bfu((unsigned short)(c >> 16)) + cw.w*bfu((unsigned short)(d >> 16));
        return bf16r(lo) | (bf16r(hi) << 16);
    };

    load_g(0);
    for (int kt = 0; kt < 36; ++kt){
        uint4 pk;
        pk.x = mix(xA0.x, xA1.x, xA2.x, xA3.x);
        pk.y = mix(xA0.y, xA1.y, xA2.y, xA3.y);
        pk.z = mix(xA0.z, xA1.z, xA2.z, xA3.z);
        pk.w = mix(xA0.w, xA1.w, xA2.w, xA3.w);
        __syncthreads();
        *(uint4*)&sA[px*64 + ((cg*8) ^ ((px & 7) << 3))] = pk;
        #pragma unroll
        for (int i = 0; i < NR; ++i){
            int s = i*512 + t;
            int row = s >> 3, c8 = (s & 7) << 3;
            *(uint4*)&sB[row*64 + (c8 ^ ((row & 7) << 3))] = bA[i];
        }
        __syncthreads();
        if (kt < 35) load_g(kt + 1);
        #pragma unroll
        for (int kk = 0; kk < 2; ++kk){
            int col = kk*32 + lk8;
            frag_ab av[2], bv[NR];
            #pragma unroll
            for (int mi = 0; mi < 2; ++mi){
                int row = wr*32 + mi*16 + lr;
                av[mi] = *(const frag_ab*)&sA[row*64 + (col ^ ((row & 7) << 3))];
            }
            #pragma unroll
            for (int ni = 0; ni < NR; ++ni){
                int row = wc*(NR*16) + ni*16 + lr;
                bv[ni] = *(const frag_ab*)&sB[row*64 + (col ^ ((row & 7) << 3))];
            }
            #pragma unroll
            for (int mi = 0; mi < 2; ++mi)
                #pragma unroll
                for (int ni = 0; ni < NR; ++ni)
                    acc[mi][ni] = __builtin_amdgcn_mfma_f32_16x16x32_bf16(av[mi], bv[ni], acc[mi][ni], 0, 0, 0);
        }
    }

    #pragma unroll
    for (int mi = 0; mi < 2; ++mi){
        int gr0 = m0 + wr*32 + mi*16 + lq*4;
        #pragma unroll
        for (int ni = 0; ni < NR; ++ni){
            int gcg = wc*(NR*16) + ni*16 + lr;
            if (gcg < Nvalid){
                float bv_ = bias ? bias[gcg] : 0.f;
                #pragma unroll
                for (int jj = 0; jj < 4; ++jj){
                    int r = gr0 + jj;
                    if (r < Mtot){
                        float v = acc[mi][ni][jj] + bv_;
                        if (gcg >= sigfrom) v = 1.f / (1.f + expf(-v));
                        C[(size_t)r*ldc + gcg] = v;
                    }
                }
            }
        }
    }

    if (DOSTATS){
        __syncthreads();
        const int b0 = m0 / HoWo;
        const int bsplit = (b0 + 1) * HoWo;
        #pragma unroll
        for (int ni = 0; ni < NR; ++ni){
            int gcl = wc*(NR*16) + ni*16 + lr;
            float s0=0.f,q0=0.f,s1=0.f,q1=0.f;
            #pragma unroll
            for (int mi = 0; mi < 2; ++mi){
                int gr0 = m0 + wr*32 + mi*16 + lq*4;
                #pragma unroll
                for (int jj = 0; jj < 4; ++jj){
                    int r = gr0 + jj;
                    if (r < Mtot){
                        float v = acc[mi][ni][jj];
                        if (r < bsplit){ s0 += v; q0 += v*v; } else { s1 += v; q1 += v*v; }
                    }
                }
            }
            int slot = wr*4 + lq;           // 0..7; distinct (slot, gcl) per writer
            float* p = &sP[((slot*BN) + gcl)*4];
            p[0]=s0; p[1]=q0; p[2]=s1; p[3]=q1;
        }
        __syncthreads();
        if (t < BN){
            float s0=0.f,q0=0.f,s1=0.f,q1=0.f;
            #pragma unroll
            for (int sl = 0; sl < 8; ++sl){
                const float* p = &sP[((sl*BN)+t)*4];
                s0+=p[0]; q0+=p[1]; s1+=p[2]; q1+=p[3];
            }
            float* o = &PART[((size_t)bl*256 + t)*4];
            o[0]=s0; o[1]=q0; o[2]=s1; o[3]=q1;
        }
    }
}

// ================= batched GN stats + normalized GAP; grid (2 batches, 7 jobs) =================
__global__ __launch_bounds__(256) void k_statsB(SD7 P, int njob){
    int job = blockIdx.y;
    if (job >= njob) return;
    const float* part = P.d[job].part;
    const float* gamma = P.d[job].gamma;
    const float* beta  = P.d[job].beta;
    float* stats = P.d[job].stats;
    float* gapn  = P.d[job].gapn;
    int nblk = P.d[job].nblk, HW = P.d[job].HW;
    int b = blockIdx.x, t = threadIdx.x;
    float s1 = 0.f, s2 = 0.f;
    for (int blk = 0; blk < nblk; ++blk){
        int b0 = (blk*64) / HW;
        float4 v = *(const float4*)&part[((size_t)blk*256 + t)*4];
        if (b0 == b)     { s1 += v.x; s2 += v.y; }
        if (b0 + 1 == b) { s1 += v.z; s2 += v.w; }
    }
    float invHW = 1.0f / (float)HW;
    float g1 = s1, g2 = s2;
    #pragma unroll
    for (int m = 8; m >= 1; m >>= 1){ g1 += __shfl_xor(g1, m, 16); g2 += __shfl_xor(g2, m, 16); }
    float mu  = g1 * invHW * (1.f/16.f);
    float var = g2 * invHW * (1.f/16.f) - mu*mu;
    float rstd = rsqrtf(var + 1e-5f);
    if ((t & 15) == 0){ int g = t >> 4; stats[(b*16+g)*2] = mu; stats[(b*16+g)*2+1] = rstd; }
    gapn[b*256 + t] = (s1*invHW - mu)*rstd*gamma[t] + beta[t];
}

// ================= batched weighted partials for resized-high GAP; grid (16,2,nlev) ============
__global__ __launch_bounds__(256) void k_wredB(WD2 P, int nlev){
    int lev = blockIdx.z;
    if (lev >= nlev) return;
    const float* Fs = P.d[lev].Fs;
    float* partw = P.d[lev].partw;
    int Hh = P.d[lev].Hh, Wh = P.d[lev].Wh, Hm = P.d[lev].Hm, Wm = P.d[lev].Wm;
    __shared__ float wy[80], wx[80];
    int t = threadIdx.x;
    int b = blockIdx.y, ch = blockIdx.x;
    if (t < Hh){
        float s = 0.f;
        for (int oy = 0; oy < Hm; ++oy){
            float ry = (float)(oy*(Hh-1)) / (float)(Hm-1);
            int y0 = (int)ry; float f = ry - (float)y0; int y1 = min(y0+1, Hh-1);
            if (y0 == t) s += 1.f - f;
            if (y1 == t) s += f;
        }
        wy[t] = s;
    }
    if (t < Wh){
        float s = 0.f;
        for (int ox = 0; ox < Wm; ++ox){
            float rx = (float)(ox*(Wh-1)) / (float)(Wm-1);
            int x0 = (int)rx; float f = rx - (float)x0; int x1 = min(x0+1, Wh-1);
            if (x0 == t) s += 1.f - f;
            if (x1 == t) s += f;
        }
        wx[t] = s;
    }
    __syncthreads();
    int HWh = Hh*Wh;
    int R = (HWh + 15) / 16;
    int r0 = ch*R, r1 = min(r0 + R, HWh);
    float s = 0.f;
    for (int r = r0; r < r1; ++r){
        int y = r / Wh, x = r - y*Wh;
        s += wy[y]*wx[x] * Fs[((size_t)b*HWh + r)*256 + t];
    }
    partw[((size_t)(b*16 + ch))*256 + t] = s;
}

// ================= batched attention + dyrelu coefficients; grid (2, nlev) =================
__global__ __launch_bounds__(256) void k_attnB(AD3 P,
    const float* __restrict__ gH, const float* __restrict__ bH,
    const float* __restrict__ sw, const float* __restrict__ sb,
    const float* __restrict__ w1, const float* __restrict__ b1v,
    const float* __restrict__ w2, const float* __restrict__ b2v,
    float* __restrict__ ABR, float* __restrict__ DYC)
{
    int lev = blockIdx.y;
    const float* gapn  = P.d[lev].gapn;
    const float* partw = P.d[lev].partw;
    const float* statsH = P.d[lev].statsH;
    float invHW = P.d[lev].invHW;
    int nbr = P.d[lev].nbr;
    float* abr = ABR + lev*8;
    float* dyc = DYC + (size_t)lev*2048;
    int b = blockIdx.x, t = threadIdx.x;
    const int B = 2;
    __shared__ float gbuf[3][256];
    __shared__ float red[256];
    __shared__ float asl[3];
    __shared__ float hh[64];
    for (int br = 0; br < nbr; ++br){
        float g;
        if (partw && br == nbr-1){
            g = 0.f;
            for (int i = 0; i < 16; ++i) g += partw[((size_t)(b*16 + i))*256 + t];
            int gi = t >> 4;
            float mu = statsH[(b*16+gi)*2], rs = statsH[(b*16+gi)*2+1];
            g = (g*invHW - mu)*rs*gH[t] + bH[t];
        } else {
            g = gapn[((size_t)br*B + b)*256 + t];
        }
        gbuf[br][t] = g;
    }
    __syncthreads();
    for (int br = 0; br < nbr; ++br){
        red[t] = gbuf[br][t] * sw[t];
        __syncthreads();
        for (int s = 128; s > 0; s >>= 1){ if (t < s) red[t] += red[t+s]; __syncthreads(); }
        if (t == 0) asl[br] = hsig(fmaxf(red[0] + sb[0], 0.f));
        __syncthreads();
    }
    float gmv = 0.f;
    for (int br = 0; br < nbr; ++br) gmv += asl[br]*gbuf[br][t];
    gmv /= (float)nbr;
    red[t] = gmv;
    __syncthreads();
    if (t < 64){
        float h = b1v[t];
        for (int c = 0; c < 256; ++c) h += w1[t*256 + c]*red[c];
        hh[t] = fmaxf(h, 0.f);
    }
    __syncthreads();
    float co[4];
    #pragma unroll
    for (int q = 0; q < 4; ++q){
        int o = q*256 + t;
        float s = b2v[o];
        for (int kk = 0; kk < 64; ++kk) s += w2[o*64 + kk]*hh[kk];
        co[q] = hsig(s);
    }
    dyc[((size_t)b*256 + t)*4 + 0] = (co[0] - 0.5f)*2.f + 1.f;
    dyc[((size_t)b*256 + t)*4 + 1] =  co[1] - 0.5f;
    dyc[((size_t)b*256 + t)*4 + 2] = (co[2] - 0.5f)*2.f;
    dyc[((size_t)b*256 + t)*4 + 3] =  co[3] - 0.5f;
    if (t < nbr) abr[b*3 + t] = asl[t];
}

// ================= batched combine (+inline high resize) + dyrelu, NHWC -> NCHW ================
__global__ __launch_bounds__(256) void k_combineB(CD3 P,
    const float* __restrict__ g0v, const float* __restrict__ b0v,
    const float* __restrict__ glv, const float* __restrict__ blv,
    const float* __restrict__ ghv, const float* __restrict__ bhv)
{
    __shared__ float TL[256*17];
    int bid = blockIdx.x, j = 0;
    #pragma unroll
    for (int i = 1; i < 3; ++i) if (bid >= P.d[i].blk0) j = i;
    const float* f0 = P.d[j].f0;
    const float* f1 = P.d[j].f1;
    const float* Fs = P.d[j].Fs;
    const float* stats = P.d[j].stats;
    const float* abr = P.d[j].abr;
    const float* dyc = P.d[j].dyc;
    float* outp = P.d[j].outp;
    int H = P.d[j].H, W = P.d[j].W, nbr = P.d[j].nbr;
    int Hh = P.d[j].Hh, Wh = P.d[j].Wh, slotH = P.d[j].slotH;
    bid -= P.d[j].blk0;

    int t = threadIdx.x;
    int nchx = (W + 15) >> 4;
    int cx = bid % nchx; int rem = bid / nchx;
    int y = rem % H; int b = rem / H;
    float a0 = abr[b*3 + 0];
    float alow = f1 ? abr[b*3 + 1] : 0.f;
    float ahigh = Fs ? abr[b*3 + (nbr-1)] : 0.f;
    float inv = 1.f / (float)nbr;
    int g = t >> 4;
    float mu0 = stats[b*32 + g*2], rs0 = stats[b*32 + g*2 + 1];
    float mu1 = 0.f, rs1 = 0.f, muh = 0.f, rsh = 0.f;
    if (f1){ mu1 = stats[64 + b*32 + g*2]; rs1 = stats[64 + b*32 + g*2 + 1]; }
    if (Fs){ muh = stats[slotH*64 + b*32 + g*2]; rsh = stats[slotH*64 + b*32 + g*2 + 1]; }
    float4 dc = *(const float4*)&dyc[((size_t)b*256 + t)*4];
    size_t HW = (size_t)H*W;
    int y0 = 0, y1 = 0; float fy = 0.f;
    if (Fs){
        float ry = (float)(y*(Hh-1)) / (float)(H-1);
        y0 = (int)ry; fy = ry - (float)y0; y1 = min(y0+1, Hh-1);
    }
    for (int i = 0; i < 16; ++i){
        int x = (cx << 4) + i;
        if (x < W){
            size_t row = (size_t)b*HW + (size_t)y*W + x;
            float v = a0 * ((f0[row*256 + t] - mu0)*rs0*g0v[t] + b0v[t]);
            if (f1) v += alow * ((f1[row*256 + t] - mu1)*rs1*glv[t] + blv[t]);
            if (Fs){
                float rx = (float)(x*(Wh-1)) / (float)(W-1);
                int x0 = (int)rx; float fx = rx - (float)x0; int x1 = min(x0+1, Wh-1);
                size_t basep = (size_t)b*Hh*Wh;
                float v00 = Fs[(basep + (size_t)y0*Wh + x0)*256 + t];
                float v01 = Fs[(basep + (size_t)y0*Wh + x1)*256 + t];
                float v10 = Fs[(basep + (size_t)y1*Wh + x0)*256 + t];
                float v11 = Fs[(basep + (size_t)y1*Wh + x1)*256 + t];
                float vi = (1.f-fy)*((1.f-fx)*v00 + fx*v01) + fy*((1.f-fx)*v10 + fx*v11);
                v += ahigh * ((vi - muh)*rsh*ghv[t] + bhv[t]);
            }
            v *= inv;
            TL[t*17 + i] = fmaxf(v*dc.x + dc.y, v*dc.z + dc.w);
        }
    }
    __syncthreads();
    int px = t & 15, cwi = t >> 4;
    for (int cb = 0; cb < 16; ++cb){
        int c = cb*16 + cwi;
        int x = (cx << 4) + px;
        if (x < W) outp[((size_t)(b*256 + c)*H + y)*W + x] = TL[c*17 + px];
    }
}

extern "C" void kernel_launch(void* const* d_in, const int* in_sizes, int n_in,
                              void* d_out, int out_size, void* d_ws, size_t ws_size,
                              hipStream_t stream)
{
    (void)in_sizes; (void)n_in; (void)out_size; (void)ws_size;
    const float* X[3]   = {(const float*)d_in[0], (const float*)d_in[1], (const float*)d_in[2]};
    const float* off_w  = (const float*)d_in[3];
    const float* off_b  = (const float*)d_in[4];
    const float* wbr[3] = {(const float*)d_in[5], (const float*)d_in[8], (const float*)d_in[11]};
    const float* gbr[3] = {(const float*)d_in[6], (const float*)d_in[9], (const float*)d_in[12]};
    const float* bbr[3] = {(const float*)d_in[7], (const float*)d_in[10], (const float*)d_in[13]};
    const float* sw  = (const float*)d_in[14];
    const float* sb  = (const float*)d_in[15];
    const float* d1w = (const float*)d_in[16];
    const float* d1b = (const float*)d_in[17];
    const float* d2w = (const float*)d_in[18];
    const float* d2b = (const float*)d_in[19];

    const int Hs[3] = {80, 40, 20};
    const int HWs[3] = {6400, 1600, 400};
    uint8_t* base = (uint8_t*)d_ws;
    size_t off = 0;
    auto alloc = [&](size_t bytes)->void*{
        off = (off + 255) & ~(size_t)255;
        void* p = base + off; off += bytes; return p;
    };
    bf16* BWO = (bf16*)alloc((size_t)64*2304*2);
    bf16* BWB[3];
    for (int i = 0; i < 3; ++i) BWB[i] = (bf16*)alloc((size_t)256*2304*2);
    bf16* X16[3];
    for (int L = 0; L < 3; ++L) X16[L] = (bf16*)alloc((size_t)2*HWs[L]*256*2);
    float* OMl[3];
    for (int L = 0; L < 3; ++L) OMl[L] = (float*)alloc((size_t)2*HWs[L]*32*4);
    float* Fm[3]; float* Fl[3]; float* Fh[3];
    for (int L = 0; L < 3; ++L) Fm[L] = (float*)alloc((size_t)2*HWs[L]*256*4);
    for (int L = 1; L < 3; ++L) Fl[L] = (float*)alloc((size_t)2*HWs[L]*256*4);
    Fl[0] = nullptr;
    for (int L = 0; L < 2; ++L) Fh[L] = (float*)alloc((size_t)2*HWs[L+1]*256*4);
    Fh[2] = nullptr;
    float* GAPN[3]; float* STATS[3];
    for (int L = 0; L < 3; ++L){
        GAPN[L]  = (float*)alloc((size_t)3*2*256*4);
        STATS[L] = (float*)alloc((size_t)3*64*4);
    }
    float* PARTW[2];
    for (int L = 0; L < 2; ++L) PARTW[L] = (float*)alloc((size_t)2*16*256*4);
    float* ABR = (float*)alloc((size_t)3*8*4);
    float* DYC = (float*)alloc((size_t)3*2048*4);

    // ---- weight conversion batch ----
    {
        VD4 P;
        int blk = 0;
        P.d[0] = {off_w, BWO, 64, 27, blk}; blk += ceildiv(64*2304, 256);
        for (int i = 0; i < 3; ++i){ P.d[1+i] = {wbr[i], BWB[i], 256, 256, blk}; blk += ceildiv(256*2304, 256); }
        k_convwB<<<blk,256,0,stream>>>(P);
    }
    // ---- X transpose batch ----
    {
        XD3 P;
        int blk = 0;
        for (int L = 0; L < 3; ++L){ P.d[L] = {X[L], X16[L], HWs[L], 2*HWs[L], blk}; blk += ceildiv(2*HWs[L], 64); }
        k_xconvB<<<blk,256,0,stream>>>(P);
    }
    const int BIG = 1 << 30;
    // ---- offset conv batch (NR=1, BN=64, sigmoid fused on mask cols) ----
    {
        FD7 P; P.n = 3;
        int blk = 0;
        for (int L = 0; L < 3; ++L){
            int H = Hs[L], HW = HWs[L], M = 2*HW;
            P.d[L] = {X16[L], nullptr, BWO, OMl[L], off_b, nullptr,
                      M, 32, 27, 18, H, H, H, H, H, HW, 1, 1, blk, 0};
            blk += ceildiv(M, 64);
        }
        k_fusedB<1,false><<<blk,512,0,stream>>>(P);
    }
    // ---- branch conv batch (NR=4, BN=256 full width, one block per 64-px tile) ----
    FD7 BP; SD7 SP;
    int nbranch = 0, bblk = 0;
    auto addBranch = [&](int L, int type){
        int H = Hs[L], HW = HWs[L];
        int slot, Ho, Wo, Hi, Wi, stride, osub, Mtot, HWo;
        const bf16* xp; float* cp;
        bool has_low = (L > 0), has_high = (L < 2);
        int nbr = 1 + (has_low?1:0) + (has_high?1:0);
        if (type == 0){ slot = 0; Ho=H; Wo=H; Hi=H; Wi=H; stride=1; osub=1; xp=X16[L]; cp=Fm[L]; }
        else if (type == 1){ slot = 1; Ho=H; Wo=H; Hi=2*H; Wi=2*H; stride=2; osub=1; xp=X16[L-1]; cp=Fl[L]; }
        else { slot = nbr-1; Ho=H/2; Wo=H/2; Hi=H/2; Wi=H/2; stride=1; osub=2; xp=X16[L+1]; cp=Fh[L]; }
        HWo = Ho*Wo; Mtot = 2*HWo;
        int nblk = ceildiv(Mtot, 64);
        float* part = (float*)alloc((size_t)nblk*256*4*4);
        BP.d[nbranch] = {xp, OMl[L], BWB[type], cp, nullptr, part,
                         Mtot, 256, 256, BIG, Ho, Wo, Hi, Wi, H, HW, stride, osub, bblk, 0};
        SP.d[nbranch] = {part, gbr[type], bbr[type], STATS[L] + slot*64, GAPN[L] + slot*512, nblk, HWo};
        bblk += nblk; ++nbranch;
    };
    for (int L = 0; L < 3; ++L){
        addBranch(L, 0);
        if (L > 0) addBranch(L, 1);
        if (L < 2) addBranch(L, 2);
    }
    BP.n = nbranch;
    k_fusedB<4,true><<<bblk,512,0,stream>>>(BP);
    k_statsB<<<dim3(2,nbranch),256,0,stream>>>(SP, nbranch);
    // ---- wred batch (levels 0,1) ----
    {
        WD2 P;
        for (int L = 0; L < 2; ++L)
            P.d[L] = {Fh[L], PARTW[L], Hs[L]/2, Hs[L]/2, Hs[L], Hs[L]};
        k_wredB<<<dim3(16,2,2),256,0,stream>>>(P, 2);
    }
    // ---- attn batch ----
    {
        AD3 P;
        for (int L = 0; L < 3; ++L){
            bool has_low = (L > 0), has_high = (L < 2);
            int nbr = 1 + (has_low?1:0) + (has_high?1:0);
            int slotH = nbr - 1;
            P.d[L] = {GAPN[L], has_high ? PARTW[L] : nullptr, STATS[L] + slotH*64,
                      1.f/(float)HWs[L], nbr};
        }
        k_attnB<<<dim3(2,3),256,0,stream>>>(P, gbr[2], bbr[2], sw, sb, d1w, d1b, d2w, d2b, ABR, DYC);
    }
    // ---- combine batch ----
    {
        CD3 P;
        int blk = 0;
        size_t lvl_off = 0;
        for (int L = 0; L < 3; ++L){
            int H = Hs[L], W = Hs[L];
            bool has_low = (L > 0), has_high = (L < 2);
            int nbr = 1 + (has_low?1:0) + (has_high?1:0);
            P.d[L] = {Fm[L], has_low ? Fl[L] : nullptr, has_high ? Fh[L] : nullptr,
                      STATS[L], ABR + L*8, DYC + (size_t)L*2048,
                      (float*)d_out + lvl_off, H, W, nbr, H/2, W/2, nbr-1, blk};
            blk += 2*H*ceildiv(W,16);
            lvl_off += (size_t)2*H*W*256;
        }
        k_combineB<<<blk,256,0,stream>>>(P, gbr[0], bbr[0], gbr[1], bbr[1], gbr[2], bbr[2]);
    }
}

// Round 9
// 384.318 us; speedup vs baseline: 1.1807x; 1.1807x over previous
//
#include <hip/hip_runtime.h>
#include <hip/hip_bf16.h>
#include <stdint.h>

typedef __hip_bfloat16 bf16;
using frag_ab = __attribute__((ext_vector_type(8))) short;
using frag_cd = __attribute__((ext_vector_type(4))) float;

static __device__ __forceinline__ float hsig(float x){
    return fminf(fmaxf((x + 3.0f) * (1.0f/6.0f), 0.0f), 1.0f);
}
static __device__ __forceinline__ float bfu(unsigned short u){
    union{ unsigned int i; float f; } c; c.i = ((unsigned int)u) << 16; return c.f;
}
// float -> bf16 bits, round-to-nearest-even
static __device__ __forceinline__ unsigned int bf16r(float f){
    union{ float f; unsigned int u; } c; c.f = f;
    return (c.u + 0x7fffu + ((c.u >> 16) & 1u)) >> 16;
}
static inline int ceildiv(int a, int b){ return (a + b - 1) / b; }

// ================= descriptor structs (passed by value in kernel args) =================
struct VD { const float* w; bf16* bw; int Opad, Ovalid, blk0; };
struct VD4 { VD d[4]; };
struct XD { const float* X; bf16* O; int HW, Ptot, blk0; };
struct XD3 { XD d[3]; };
struct FD {
    const bf16* X16; const float* OM; const bf16* Bw;
    float* C; const float* bias; float* PART;
    int Mtot, ldc, Nvalid, sigfrom;
    int Ho, Wo, Hi, Wi, Wm, HmWm, stride, osub, blk0, Pin;   // Pin = input pixel count 2*Hi*Wi
};
struct FD7 { FD d[7]; int n; };
struct SD { const float* part; const float* gamma; const float* beta;
            float* stats; float* gapn; int nblk, HW; };
struct SD7 { SD d[7]; };
struct WD { const float* Fs; float* partw; int Hh, Wh, Hm, Wm; };
struct WD2 { WD d[2]; };
struct AD { const float* gapn; const float* partw; const float* statsH; float invHW; int nbr; };
struct AD3 { AD d[3]; };
struct CD { const float* f0; const float* f1; const float* Fs;
            const float* stats; const float* abr; const float* dyc; float* outp;
            int H, W, nbr, Hh, Wh, slotH, blk0; };
struct CD3 { CD d[3]; };

// ================= batched weight conversion: w[O][256][3][3] -> bw[Opad][2304], K=k*256+c ======
__global__ __launch_bounds__(256) void k_convwB(VD4 P){
    int bx = blockIdx.x, j = 0;
    #pragma unroll
    for (int i = 1; i < 4; ++i) if (bx >= P.d[i].blk0) j = i;
    const float* w = P.d[j].w; bf16* bw = P.d[j].bw;
    int Opad = P.d[j].Opad, Ovalid = P.d[j].Ovalid;
    int i = (bx - P.d[j].blk0)*256 + threadIdx.x;
    if (i >= Opad*2304) return;
    int o = i / 2304, r = i - o*2304;
    int k = r >> 8, c = r & 255;
    float v = 0.f;
    if (o < Ovalid) v = w[((size_t)(o*256 + c))*9 + k];
    bw[i] = __float2bfloat16(v);
}

// ================= batched X fp32 NCHW -> bf16 chunk-major [32][Ptot][8] =================
__global__ __launch_bounds__(256) void k_xconvB(XD3 P){
    __shared__ bf16 T[64][264];
    int bx = blockIdx.x, j = 0;
    #pragma unroll
    for (int i = 1; i < 3; ++i) if (bx >= P.d[i].blk0) j = i;
    const float* X = P.d[j].X; bf16* O = P.d[j].O;
    int HW = P.d[j].HW, Ptot = P.d[j].Ptot;
    int t = threadIdx.x;
    int pbase = (bx - P.d[j].blk0)*64;
    int px = t & 63, cg = t >> 6;
    int p = pbase + px;
    if (p < Ptot){
        int b = p / HW, rem = p - b*HW;
        const float* xb = X + (size_t)b*256*HW + rem;
        for (int c = cg; c < 256; c += 4)
            T[px][c] = __float2bfloat16(xb[(size_t)c*HW]);
    }
    __syncthreads();
    // write chunk-major: per wave, fixed chunk, 64 consecutive pixels -> fully coalesced
    for (int jj = 0; jj < 8; ++jj){
        int ck = jj*4 + (t >> 6);
        int opx = t & 63;
        int op = pbase + opx;
        if (op < Ptot){
            uint4 u = *(const uint4*)&T[opx][ck << 3];
            *(uint4*)&O[((size_t)ck*Ptot + op)*8] = u;
        }
    }
}

// ================= batched fused deformable-gather + NT GEMM (+GN partials) =================
// Block: 512 thr (8 waves, 2x4 wave grid). Tile 64 px x BN (BN = NR*64), full N per block.
// X16 is chunk-major [32][Pin][8]: corner loads are 16B/pixel, adjacent lanes adjacent pixels.
// PLAIN: no offsets (ly=lx=0, w00 in {0,1}) -> load corner 0 only, no bilinear mix.
template<int NR, bool DOSTATS, bool PLAIN>
__global__ __launch_bounds__(512) void k_fusedB(FD7 P){
    constexpr int BN  = NR*64;
    constexpr int SMEMB = (64*64 + BN*64)*2 + 9*64*32;
    __shared__ __align__(16) char smem[SMEMB];
    bf16* sA = (bf16*)smem;
    bf16* sB = sA + 64*64;
    int*  smi = (int*)(smem + (size_t)(64*64 + BN*64)*2);
    float* smw = (float*)(smi + 9*64*4);
    float* sP = (float*)smem;

    int bx = blockIdx.x, j = 0;
    #pragma unroll
    for (int i = 1; i < 7; ++i) if (i < P.n && bx >= P.d[i].blk0) j = i;
    const bf16* __restrict__ X16 = P.d[j].X16;
    const float* __restrict__ OM = P.d[j].OM;
    const bf16* __restrict__ Bw  = P.d[j].Bw;
    float* __restrict__ C        = P.d[j].C;
    const float* __restrict__ bias = P.d[j].bias;
    float* __restrict__ PART     = P.d[j].PART;
    const int Mtot = P.d[j].Mtot, ldc = P.d[j].ldc, Nvalid = P.d[j].Nvalid, sigfrom = P.d[j].sigfrom;
    const int Ho = P.d[j].Ho, Wo = P.d[j].Wo, Hi = P.d[j].Hi, Wi = P.d[j].Wi;
    const int Wm = P.d[j].Wm, HmWm = P.d[j].HmWm, stride = P.d[j].stride, osub = P.d[j].osub;
    const size_t Pin8 = (size_t)P.d[j].Pin * 8;
    const int bl = bx - P.d[j].blk0;

    const int t = threadIdx.x;
    const int m0 = bl * 64;
    const int HoWo = Ho * Wo;
    const int HiWi = Hi * Wi;
    const int px = t & 63;
    const int cg = t >> 6;          // wave id; channel chunk-of-8 within the 64-ch K-slice

    // ---- meta: per (pixel, tap) 4 corner pixel indices + 4 weights ----
    for (int i = t; i < 576; i += 512){
        int p_ = i & 63, k = i >> 6;
        int p = m0 + p_;
        bool pv = p < Mtot;
        int pp = pv ? p : 0;
        int b = pp / HoWo; int r = pp - b*HoWo; int y = r / Wo; int x = r - y*Wo;
        float offy = 0.f, offx = 0.f, mk = 1.f;
        if (OM){
            size_t ob = ((size_t)b*HmWm + (size_t)(y*osub)*Wm + (size_t)(x*osub)) * 32;
            offy = OM[ob + 2*k]; offx = OM[ob + 2*k + 1]; mk = OM[ob + 18 + k];
        }
        if (!pv) mk = 0.f;
        int kh = k/3, kw = k - kh*3;
        float py = (float)(y*stride - 1 + kh) + offy;
        float pxf = (float)(x*stride - 1 + kw) + offx;
        float y0f = floorf(py), x0f = floorf(pxf);
        float ly = py - y0f, lx = pxf - x0f;
        int y0 = (int)y0f, x0 = (int)x0f;
        int y1 = y0 + 1, x1 = x0 + 1;
        float vy0 = (y0 >= 0 && y0 < Hi) ? 1.f : 0.f;
        float vy1 = (y1 >= 0 && y1 < Hi) ? 1.f : 0.f;
        float vx0 = (x0 >= 0 && x0 < Wi) ? 1.f : 0.f;
        float vx1 = (x1 >= 0 && x1 < Wi) ? 1.f : 0.f;
        int y0c = min(max(y0,0),Hi-1), y1c = min(max(y1,0),Hi-1);
        int x0c = min(max(x0,0),Wi-1), x1c = min(max(x1,0),Wi-1);
        int base = b*HiWi;
        smi[(k*64+p_)*4+0] = base + y0c*Wi + x0c;
        smi[(k*64+p_)*4+1] = base + y0c*Wi + x1c;
        smi[(k*64+p_)*4+2] = base + y1c*Wi + x0c;
        smi[(k*64+p_)*4+3] = base + y1c*Wi + x1c;
        smw[(k*64+p_)*4+0] = (1.f-ly)*(1.f-lx)*mk*vy0*vx0;
        smw[(k*64+p_)*4+1] = (1.f-ly)*lx*mk*vy0*vx1;
        smw[(k*64+p_)*4+2] = ly*(1.f-lx)*mk*vy1*vx0;
        smw[(k*64+p_)*4+3] = ly*lx*mk*vy1*vx1;
    }
    __syncthreads();

    frag_cd acc[2][NR];
    frag_cd zero = {0.f,0.f,0.f,0.f};
    #pragma unroll
    for (int i = 0; i < 2; ++i)
        #pragma unroll
        for (int jj = 0; jj < NR; ++jj) acc[i][jj] = zero;

    const int l = t & 63;
    const int wr = cg >> 2, wc = cg & 3;     // 2x4 wave grid
    const int lr = l & 15, lq = l >> 4;
    const int lk8 = lq * 8;

    uint4 bA[NR];
    uint4 xA0, xA1, xA2, xA3;
    float4 cw;

    auto load_g = [&](int kt){
        int k = kt >> 2;
        int chunk = (kt & 3)*8 + cg;
        const bf16* Xc = X16 + (size_t)chunk * Pin8;
        int4 ci = *(const int4*)&smi[(k*64+px)*4];
        cw = *(const float4*)&smw[(k*64+px)*4];
        xA0 = *(const uint4*)&Xc[(size_t)ci.x * 8];
        if (!PLAIN){
            xA1 = *(const uint4*)&Xc[(size_t)ci.y * 8];
            xA2 = *(const uint4*)&Xc[(size_t)ci.z * 8];
            xA3 = *(const uint4*)&Xc[(size_t)ci.w * 8];
        }
        #pragma unroll
        for (int i = 0; i < NR; ++i){
            int s = i*512 + t;
            int row = s >> 3, c8 = (s & 7) << 3;
            bA[i] = *(const uint4*)&Bw[(size_t)row*2304 + kt*64 + c8];
        }
    };

    auto mix = [&](unsigned int a, unsigned int b, unsigned int c, unsigned int d)->unsigned int{
        float lo = cw.x*bfu((unsigned short)(a & 0xffffu)) + cw.y*bfu((unsigned short)(b & 0xffffu))
                 + cw.z*bfu((unsigned short)(c & 0xffffu)) + cw.w*bfu((unsigned short)(d & 0xffffu));
        float hi = cw.x*bfu((unsigned short)(a >> 16)) + cw.y*bfu((unsigned short)(b >> 16))
                 + cw.z*bfu((unsigned short)(c >> 16)) + cw.w*bfu((unsigned short)(d >> 16));
        return bf16r(lo) | (bf16r(hi) << 16);
    };

    load_g(0);
    for (int kt = 0; kt < 36; ++kt){
        uint4 pk;
        if (PLAIN){
            uint4 z = {0u,0u,0u,0u};
            pk = (cw.x > 0.5f) ? xA0 : z;
        } else {
            pk.x = mix(xA0.x, xA1.x, xA2.x, xA3.x);
            pk.y = mix(xA0.y, xA1.y, xA2.y, xA3.y);
            pk.z = mix(xA0.z, xA1.z, xA2.z, xA3.z);
            pk.w = mix(xA0.w, xA1.w, xA2.w, xA3.w);
        }
        __syncthreads();
        *(uint4*)&sA[px*64 + ((cg*8) ^ ((px & 7) << 3))] = pk;
        #pragma unroll
        for (int i = 0; i < NR; ++i){
            int s = i*512 + t;
            int row = s >> 3, c8 = (s & 7) << 3;
            *(uint4*)&sB[row*64 + (c8 ^ ((row & 7) << 3))] = bA[i];
        }
        __syncthreads();
        if (kt < 35) load_g(kt + 1);
        #pragma unroll
        for (int kk = 0; kk < 2; ++kk){
            int col = kk*32 + lk8;
            frag_ab av[2], bv[NR];
            #pragma unroll
            for (int mi = 0; mi < 2; ++mi){
                int row = wr*32 + mi*16 + lr;
                av[mi] = *(const frag_ab*)&sA[row*64 + (col ^ ((row & 7) << 3))];
            }
            #pragma unroll
            for (int ni = 0; ni < NR; ++ni){
                int row = wc*(NR*16) + ni*16 + lr;
                bv[ni] = *(const frag_ab*)&sB[row*64 + (col ^ ((row & 7) << 3))];
            }
            #pragma unroll
            for (int mi = 0; mi < 2; ++mi)
                #pragma unroll
                for (int ni = 0; ni < NR; ++ni)
                    acc[mi][ni] = __builtin_amdgcn_mfma_f32_16x16x32_bf16(av[mi], bv[ni], acc[mi][ni], 0, 0, 0);
        }
    }

    #pragma unroll
    for (int mi = 0; mi < 2; ++mi){
        int gr0 = m0 + wr*32 + mi*16 + lq*4;
        #pragma unroll
        for (int ni = 0; ni < NR; ++ni){
            int gcg = wc*(NR*16) + ni*16 + lr;
            if (gcg < Nvalid){
                float bv_ = bias ? bias[gcg] : 0.f;
                #pragma unroll
                for (int jj = 0; jj < 4; ++jj){
                    int r = gr0 + jj;
                    if (r < Mtot){
                        float v = acc[mi][ni][jj] + bv_;
                        if (gcg >= sigfrom) v = 1.f / (1.f + expf(-v));
                        C[(size_t)r*ldc + gcg] = v;
                    }
                }
            }
        }
    }

    if (DOSTATS){
        __syncthreads();
        const int b0 = m0 / HoWo;
        const int bsplit = (b0 + 1) * HoWo;
        #pragma unroll
        for (int ni = 0; ni < NR; ++ni){
            int gcl = wc*(NR*16) + ni*16 + lr;
            float s0=0.f,q0=0.f,s1=0.f,q1=0.f;
            #pragma unroll
            for (int mi = 0; mi < 2; ++mi){
                int gr0 = m0 + wr*32 + mi*16 + lq*4;
                #pragma unroll
                for (int jj = 0; jj < 4; ++jj){
                    int r = gr0 + jj;
                    if (r < Mtot){
                        float v = acc[mi][ni][jj];
                        if (r < bsplit){ s0 += v; q0 += v*v; } else { s1 += v; q1 += v*v; }
                    }
                }
            }
            int slot = wr*4 + lq;
            float* p = &sP[((slot*BN) + gcl)*4];
            p[0]=s0; p[1]=q0; p[2]=s1; p[3]=q1;
        }
        __syncthreads();
        if (t < BN){
            float s0=0.f,q0=0.f,s1=0.f,q1=0.f;
            #pragma unroll
            for (int sl = 0; sl < 8; ++sl){
                const float* p = &sP[((sl*BN)+t)*4];
                s0+=p[0]; q0+=p[1]; s1+=p[2]; q1+=p[3];
            }
            float* o = &PART[((size_t)bl*256 + t)*4];
            o[0]=s0; o[1]=q0; o[2]=s1; o[3]=q1;
        }
    }
}

// ================= batched GN stats + normalized GAP; grid (2 batches, 7 jobs) =================
__global__ __launch_bounds__(256) void k_statsB(SD7 P, int njob){
    int job = blockIdx.y;
    if (job >= njob) return;
    const float* part = P.d[job].part;
    const float* gamma = P.d[job].gamma;
    const float* beta  = P.d[job].beta;
    float* stats = P.d[job].stats;
    float* gapn  = P.d[job].gapn;
    int nblk = P.d[job].nblk, HW = P.d[job].HW;
    int b = blockIdx.x, t = threadIdx.x;
    float s1 = 0.f, s2 = 0.f;
    for (int blk = 0; blk < nblk; ++blk){
        int b0 = (blk*64) / HW;
        float4 v = *(const float4*)&part[((size_t)blk*256 + t)*4];
        if (b0 == b)     { s1 += v.x; s2 += v.y; }
        if (b0 + 1 == b) { s1 += v.z; s2 += v.w; }
    }
    float invHW = 1.0f / (float)HW;
    float g1 = s1, g2 = s2;
    #pragma unroll
    for (int m = 8; m >= 1; m >>= 1){ g1 += __shfl_xor(g1, m, 16); g2 += __shfl_xor(g2, m, 16); }
    float mu  = g1 * invHW * (1.f/16.f);
    float var = g2 * invHW * (1.f/16.f) - mu*mu;
    float rstd = rsqrtf(var + 1e-5f);
    if ((t & 15) == 0){ int g = t >> 4; stats[(b*16+g)*2] = mu; stats[(b*16+g)*2+1] = rstd; }
    gapn[b*256 + t] = (s1*invHW - mu)*rstd*gamma[t] + beta[t];
}

// ================= batched weighted partials for resized-high GAP; grid (16,2,nlev) ============
__global__ __launch_bounds__(256) void k_wredB(WD2 P, int nlev){
    int lev = blockIdx.z;
    if (lev >= nlev) return;
    const float* Fs = P.d[lev].Fs;
    float* partw = P.d[lev].partw;
    int Hh = P.d[lev].Hh, Wh = P.d[lev].Wh, Hm = P.d[lev].Hm, Wm = P.d[lev].Wm;
    __shared__ float wy[80], wx[80];
    int t = threadIdx.x;
    int b = blockIdx.y, ch = blockIdx.x;
    if (t < Hh){
        float s = 0.f;
        for (int oy = 0; oy < Hm; ++oy){
            float ry = (float)(oy*(Hh-1)) / (float)(Hm-1);
            int y0 = (int)ry; float f = ry - (float)y0; int y1 = min(y0+1, Hh-1);
            if (y0 == t) s += 1.f - f;
            if (y1 == t) s += f;
        }
        wy[t] = s;
    }
    if (t < Wh){
        float s = 0.f;
        for (int ox = 0; ox < Wm; ++ox){
            float rx = (float)(ox*(Wh-1)) / (float)(Wm-1);
            int x0 = (int)rx; float f = rx - (float)x0; int x1 = min(x0+1, Wh-1);
            if (x0 == t) s += 1.f - f;
            if (x1 == t) s += f;
        }
        wx[t] = s;
    }
    __syncthreads();
    int HWh = Hh*Wh;
    int R = (HWh + 15) / 16;
    int r0 = ch*R, r1 = min(r0 + R, HWh);
    float s = 0.f;
    for (int r = r0; r < r1; ++r){
        int y = r / Wh, x = r - y*Wh;
        s += wy[y]*wx[x] * Fs[((size_t)b*HWh + r)*256 + t];
    }
    partw[((size_t)(b*16 + ch))*256 + t] = s;
}

// ================= batched attention + dyrelu coefficients; grid (2, nlev) =================
__global__ __launch_bounds__(256) void k_attnB(AD3 P,
    const float* __restrict__ gH, const float* __restrict__ bH,
    const float* __restrict__ sw, const float* __restrict__ sb,
    const float* __restrict__ w1, const float* __restrict__ b1v,
    const float* __restrict__ w2, const float* __restrict__ b2v,
    float* __restrict__ ABR, float* __restrict__ DYC)
{
    int lev = blockIdx.y;
    const float* gapn  = P.d[lev].gapn;
    const float* partw = P.d[lev].partw;
    const float* statsH = P.d[lev].statsH;
    float invHW = P.d[lev].invHW;
    int nbr = P.d[lev].nbr;
    float* abr = ABR + lev*8;
    float* dyc = DYC + (size_t)lev*2048;
    int b = blockIdx.x, t = threadIdx.x;
    const int B = 2;
    __shared__ float gbuf[3][256];
    __shared__ float red[256];
    __shared__ float asl[3];
    __shared__ float hh[64];
    for (int br = 0; br < nbr; ++br){
        float g;
        if (partw && br == nbr-1){
            g = 0.f;
            for (int i = 0; i < 16; ++i) g += partw[((size_t)(b*16 + i))*256 + t];
            int gi = t >> 4;
            float mu = statsH[(b*16+gi)*2], rs = statsH[(b*16+gi)*2+1];
            g = (g*invHW - mu)*rs*gH[t] + bH[t];
        } else {
            g = gapn[((size_t)br*B + b)*256 + t];
        }
        gbuf[br][t] = g;
    }
    __syncthreads();
    for (int br = 0; br < nbr; ++br){
        red[t] = gbuf[br][t] * sw[t];
        __syncthreads();
        for (int s = 128; s > 0; s >>= 1){ if (t < s) red[t] += red[t+s]; __syncthreads(); }
        if (t == 0) asl[br] = hsig(fmaxf(red[0] + sb[0], 0.f));
        __syncthreads();
    }
    float gmv = 0.f;
    for (int br = 0; br < nbr; ++br) gmv += asl[br]*gbuf[br][t];
    gmv /= (float)nbr;
    red[t] = gmv;
    __syncthreads();
    if (t < 64){
        float h = b1v[t];
        for (int c = 0; c < 256; ++c) h += w1[t*256 + c]*red[c];
        hh[t] = fmaxf(h, 0.f);
    }
    __syncthreads();
    float co[4];
    #pragma unroll
    for (int q = 0; q < 4; ++q){
        int o = q*256 + t;
        float s = b2v[o];
        for (int kk = 0; kk < 64; ++kk) s += w2[o*64 + kk]*hh[kk];
        co[q] = hsig(s);
    }
    dyc[((size_t)b*256 + t)*4 + 0] = (co[0] - 0.5f)*2.f + 1.f;
    dyc[((size_t)b*256 + t)*4 + 1] =  co[1] - 0.5f;
    dyc[((size_t)b*256 + t)*4 + 2] = (co[2] - 0.5f)*2.f;
    dyc[((size_t)b*256 + t)*4 + 3] =  co[3] - 0.5f;
    if (t < nbr) abr[b*3 + t] = asl[t];
}

// ================= batched combine (+inline high resize) + dyrelu, NHWC -> NCHW ================
__global__ __launch_bounds__(256) void k_combineB(CD3 P,
    const float* __restrict__ g0v, const float* __restrict__ b0v,
    const float* __restrict__ glv, const float* __restrict__ blv,
    const float* __restrict__ ghv, const float* __restrict__ bhv)
{
    __shared__ float TL[256*17];
    int bid = blockIdx.x, j = 0;
    #pragma unroll
    for (int i = 1; i < 3; ++i) if (bid >= P.d[i].blk0) j = i;
    const float* f0 = P.d[j].f0;
    const float* f1 = P.d[j].f1;
    const float* Fs = P.d[j].Fs;
    const float* stats = P.d[j].stats;
    const float* abr = P.d[j].abr;
    const float* dyc = P.d[j].dyc;
    float* outp = P.d[j].outp;
    int H = P.d[j].H, W = P.d[j].W, nbr = P.d[j].nbr;
    int Hh = P.d[j].Hh, Wh = P.d[j].Wh, slotH = P.d[j].slotH;
    bid -= P.d[j].blk0;

    int t = threadIdx.x;
    int nchx = (W + 15) >> 4;
    int cx = bid % nchx; int rem = bid / nchx;
    int y = rem % H; int b = rem / H;
    float a0 = abr[b*3 + 0];
    float alow = f1 ? abr[b*3 + 1] : 0.f;
    float ahigh = Fs ? abr[b*3 + (nbr-1)] : 0.f;
    float inv = 1.f / (float)nbr;
    int g = t >> 4;
    float mu0 = stats[b*32 + g*2], rs0 = stats[b*32 + g*2 + 1];
    float mu1 = 0.f, rs1 = 0.f, muh = 0.f, rsh = 0.f;
    if (f1){ mu1 = stats[64 + b*32 + g*2]; rs1 = stats[64 + b*32 + g*2 + 1]; }
    if (Fs){ muh = stats[slotH*64 + b*32 + g*2]; rsh = stats[slotH*64 + b*32 + g*2 + 1]; }
    float4 dc = *(const float4*)&dyc[((size_t)b*256 + t)*4];
    size_t HW = (size_t)H*W;
    int y0 = 0, y1 = 0; float fy = 0.f;
    if (Fs){
        float ry = (float)(y*(Hh-1)) / (float)(H-1);
        y0 = (int)ry; fy = ry - (float)y0; y1 = min(y0+1, Hh-1);
    }
    for (int i = 0; i < 16; ++i){
        int x = (cx << 4) + i;
        if (x < W){
            size_t row = (size_t)b*HW + (size_t)y*W + x;
            float v = a0 * ((f0[row*256 + t] - mu0)*rs0*g0v[t] + b0v[t]);
            if (f1) v += alow * ((f1[row*256 + t] - mu1)*rs1*glv[t] + blv[t]);
            if (Fs){
                float rx = (float)(x*(Wh-1)) / (float)(W-1);
                int x0 = (int)rx; float fx = rx - (float)x0; int x1 = min(x0+1, Wh-1);
                size_t basep = (size_t)b*Hh*Wh;
                float v00 = Fs[(basep + (size_t)y0*Wh + x0)*256 + t];
                float v01 = Fs[(basep + (size_t)y0*Wh + x1)*256 + t];
                float v10 = Fs[(basep + (size_t)y1*Wh + x0)*256 + t];
                float v11 = Fs[(basep + (size_t)y1*Wh + x1)*256 + t];
                float vi = (1.f-fy)*((1.f-fx)*v00 + fx*v01) + fy*((1.f-fx)*v10 + fx*v11);
                v += ahigh * ((vi - muh)*rsh*ghv[t] + bhv[t]);
            }
            v *= inv;
            TL[t*17 + i] = fmaxf(v*dc.x + dc.y, v*dc.z + dc.w);
        }
    }
    __syncthreads();
    int px = t & 15, cwi = t >> 4;
    for (int cb = 0; cb < 16; ++cb){
        int c = cb*16 + cwi;
        int x = (cx << 4) + px;
        if (x < W) outp[((size_t)(b*256 + c)*H + y)*W + x] = TL[c*17 + px];
    }
}

extern "C" void kernel_launch(void* const* d_in, const int* in_sizes, int n_in,
                              void* d_out, int out_size, void* d_ws, size_t ws_size,
                              hipStream_t stream)
{
    (void)in_sizes; (void)n_in; (void)out_size; (void)ws_size;
    const float* X[3]   = {(const float*)d_in[0], (const float*)d_in[1], (const float*)d_in[2]};
    const float* off_w  = (const float*)d_in[3];
    const float* off_b  = (const float*)d_in[4];
    const float* wbr[3] = {(const float*)d_in[5], (const float*)d_in[8], (const float*)d_in[11]};
    const float* gbr[3] = {(const float*)d_in[6], (const float*)d_in[9], (const float*)d_in[12]};
    const float* bbr[3] = {(const float*)d_in[7], (const float*)d_in[10], (const float*)d_in[13]};
    const float* sw  = (const float*)d_in[14];
    const float* sb  = (const float*)d_in[15];
    const float* d1w = (const float*)d_in[16];
    const float* d1b = (const float*)d_in[17];
    const float* d2w = (const float*)d_in[18];
    const float* d2b = (const float*)d_in[19];

    const int Hs[3] = {80, 40, 20};
    const int HWs[3] = {6400, 1600, 400};
    uint8_t* base = (uint8_t*)d_ws;
    size_t off = 0;
    auto alloc = [&](size_t bytes)->void*{
        off = (off + 255) & ~(size_t)255;
        void* p = base + off; off += bytes; return p;
    };
    bf16* BWO = (bf16*)alloc((size_t)64*2304*2);
    bf16* BWB[3];
    for (int i = 0; i < 3; ++i) BWB[i] = (bf16*)alloc((size_t)256*2304*2);
    bf16* X16[3];
    for (int L = 0; L < 3; ++L) X16[L] = (bf16*)alloc((size_t)2*HWs[L]*256*2);
    float* OMl[3];
    for (int L = 0; L < 3; ++L) OMl[L] = (float*)alloc((size_t)2*HWs[L]*32*4);
    float* Fm[3]; float* Fl[3]; float* Fh[3];
    for (int L = 0; L < 3; ++L) Fm[L] = (float*)alloc((size_t)2*HWs[L]*256*4);
    for (int L = 1; L < 3; ++L) Fl[L] = (float*)alloc((size_t)2*HWs[L]*256*4);
    Fl[0] = nullptr;
    for (int L = 0; L < 2; ++L) Fh[L] = (float*)alloc((size_t)2*HWs[L+1]*256*4);
    Fh[2] = nullptr;
    float* GAPN[3]; float* STATS[3];
    for (int L = 0; L < 3; ++L){
        GAPN[L]  = (float*)alloc((size_t)3*2*256*4);
        STATS[L] = (float*)alloc((size_t)3*64*4);
    }
    float* PARTW[2];
    for (int L = 0; L < 2; ++L) PARTW[L] = (float*)alloc((size_t)2*16*256*4);
    float* ABR = (float*)alloc((size_t)3*8*4);
    float* DYC = (float*)alloc((size_t)3*2048*4);

    // ---- weight conversion batch ----
    {
        VD4 P;
        int blk = 0;
        P.d[0] = {off_w, BWO, 64, 27, blk}; blk += ceildiv(64*2304, 256);
        for (int i = 0; i < 3; ++i){ P.d[1+i] = {wbr[i], BWB[i], 256, 256, blk}; blk += ceildiv(256*2304, 256); }
        k_convwB<<<blk,256,0,stream>>>(P);
    }
    // ---- X transpose batch (chunk-major output) ----
    {
        XD3 P;
        int blk = 0;
        for (int L = 0; L < 3; ++L){ P.d[L] = {X[L], X16[L], HWs[L], 2*HWs[L], blk}; blk += ceildiv(2*HWs[L], 64); }
        k_xconvB<<<blk,256,0,stream>>>(P);
    }
    const int BIG = 1 << 30;
    // ---- offset conv batch (NR=1, PLAIN im2col, sigmoid fused on mask cols) ----
    {
        FD7 P; P.n = 3;
        int blk = 0;
        for (int L = 0; L < 3; ++L){
            int H = Hs[L], HW = HWs[L], M = 2*HW;
            P.d[L] = {X16[L], nullptr, BWO, OMl[L], off_b, nullptr,
                      M, 32, 27, 18, H, H, H, H, H, HW, 1, 1, blk, M};
            blk += ceildiv(M, 64);
        }
        k_fusedB<1,false,true><<<blk,512,0,stream>>>(P);
    }
    // ---- branch conv batch (NR=4, BN=256 full width, one block per 64-px tile) ----
    FD7 BP; SD7 SP;
    int nbranch = 0, bblk = 0;
    auto addBranch = [&](int L, int type){
        int H = Hs[L], HW = HWs[L];
        int slot, Ho, Wo, Hi, Wi, stride, osub, Mtot, HWo;
        const bf16* xp; float* cp;
        bool has_low = (L > 0), has_high = (L < 2);
        int nbr = 1 + (has_low?1:0) + (has_high?1:0);
        if (type == 0){ slot = 0; Ho=H; Wo=H; Hi=H; Wi=H; stride=1; osub=1; xp=X16[L]; cp=Fm[L]; }
        else if (type == 1){ slot = 1; Ho=H; Wo=H; Hi=2*H; Wi=2*H; stride=2; osub=1; xp=X16[L-1]; cp=Fl[L]; }
        else { slot = nbr-1; Ho=H/2; Wo=H/2; Hi=H/2; Wi=H/2; stride=1; osub=2; xp=X16[L+1]; cp=Fh[L]; }
        HWo = Ho*Wo; Mtot = 2*HWo;
        int nblk = ceildiv(Mtot, 64);
        float* part = (float*)alloc((size_t)nblk*256*4*4);
        BP.d[nbranch] = {xp, OMl[L], BWB[type], cp, nullptr, part,
                         Mtot, 256, 256, BIG, Ho, Wo, Hi, Wi, H, HW, stride, osub, bblk, 2*Hi*Wi};
        SP.d[nbranch] = {part, gbr[type], bbr[type], STATS[L] + slot*64, GAPN[L] + slot*512, nblk, HWo};
        bblk += nblk; ++nbranch;
    };
    for (int L = 0; L < 3; ++L){
        addBranch(L, 0);
        if (L > 0) addBranch(L, 1);
        if (L < 2) addBranch(L, 2);
    }
    BP.n = nbranch;
    k_fusedB<4,true,false><<<bblk,512,0,stream>>>(BP);
    k_statsB<<<dim3(2,nbranch),256,0,stream>>>(SP, nbranch);
    // ---- wred batch (levels 0,1) ----
    {
        WD2 P;
        for (int L = 0; L < 2; ++L)
            P.d[L] = {Fh[L], PARTW[L], Hs[L]/2, Hs[L]/2, Hs[L], Hs[L]};
        k_wredB<<<dim3(16,2,2),256,0,stream>>>(P, 2);
    }
    // ---- attn batch ----
    {
        AD3 P;
        for (int L = 0; L < 3; ++L){
            bool has_low = (L > 0), has_high = (L < 2);
            int nbr = 1 + (has_low?1:0) + (has_high?1:0);
            int slotH = nbr - 1;
            P.d[L] = {GAPN[L], has_high ? PARTW[L] : nullptr, STATS[L] + slotH*64,
                      1.f/(float)HWs[L], nbr};
        }
        k_attnB<<<dim3(2,3),256,0,stream>>>(P, gbr[2], bbr[2], sw, sb, d1w, d1b, d2w, d2b, ABR, DYC);
    }
    // ---- combine batch ----
    {
        CD3 P;
        int blk = 0;
        size_t lvl_off = 0;
        for (int L = 0; L < 3; ++L){
            int H = Hs[L], W = Hs[L];
            bool has_low = (L > 0), has_high = (L < 2);
            int nbr = 1 + (has_low?1:0) + (has_high?1:0);
            P.d[L] = {Fm[L], has_low ? Fl[L] : nullptr, has_high ? Fh[L] : nullptr,
                      STATS[L], ABR + L*8, DYC + (size_t)L*2048,
                      (float*)d_out + lvl_off, H, W, nbr, H/2, W/2, nbr-1, blk};
            blk += 2*H*ceildiv(W,16);
            lvl_off += (size_t)2*H*W*256;
        }
        k_combineB<<<blk,256,0,stream>>>(P, gbr[0], bbr[0], gbr[1], bbr[1], gbr[2], bbr[2]);
    }
}

// Round 10
// 270.170 us; speedup vs baseline: 1.6795x; 1.4225x over previous
//
#include <hip/hip_runtime.h>
#include <hip/hip_bf16.h>
#include <stdint.h>

typedef __hip_bfloat16 bf16;
using frag_ab = __attribute__((ext_vector_type(8))) short;
using frag_cd = __attribute__((ext_vector_type(4))) float;

static __device__ __forceinline__ float hsig(float x){
    return fminf(fmaxf((x + 3.0f) * (1.0f/6.0f), 0.0f), 1.0f);
}
static __device__ __forceinline__ float bfu(unsigned short u){
    union{ unsigned int i; float f; } c; c.i = ((unsigned int)u) << 16; return c.f;
}
static __device__ __forceinline__ unsigned int bf16r(float f){
    union{ float f; unsigned int u; } c; c.f = f;
    return (c.u + 0x7fffu + ((c.u >> 16) & 1u)) >> 16;
}
static __device__ __forceinline__ unsigned int mix4(float4 cw, unsigned int a, unsigned int b,
                                                    unsigned int c, unsigned int d){
    float lo = cw.x*bfu((unsigned short)(a & 0xffffu)) + cw.y*bfu((unsigned short)(b & 0xffffu))
             + cw.z*bfu((unsigned short)(c & 0xffffu)) + cw.w*bfu((unsigned short)(d & 0xffffu));
    float hi = cw.x*bfu((unsigned short)(a >> 16)) + cw.y*bfu((unsigned short)(b >> 16))
             + cw.z*bfu((unsigned short)(c >> 16)) + cw.w*bfu((unsigned short)(d >> 16));
    return bf16r(lo) | (bf16r(hi) << 16);
}
static __device__ __forceinline__ void cwrite4(float* __restrict__ C, int Mtot, int gr0, int gcg,
                                               frag_cd a){
    #pragma unroll
    for (int jj = 0; jj < 4; ++jj){ int r = gr0 + jj; if (r < Mtot) C[(size_t)r*256 + gcg] = a[jj]; }
}
static __device__ __forceinline__ float4 statacc(float4 s, int gr0, int Mtot, int bsplit, frag_cd a){
    #pragma unroll
    for (int jj = 0; jj < 4; ++jj){
        int r = gr0 + jj;
        if (r < Mtot){ float v = a[jj]; if (r < bsplit){ s.x += v; s.y += v*v; } else { s.z += v; s.w += v*v; } }
    }
    return s;
}
static inline int ceildiv(int a, int b){ return (a + b - 1) / b; }

// ================= descriptor structs =================
struct VD { const float* w; bf16* bw; int Opad, Ovalid, blk0; };
struct VD4 { VD d[4]; };
struct XD { const float* X; bf16* O; int HW, Ptot, blk0; };
struct XD3 { XD d[3]; };
struct FD {
    const bf16* X16; const float* OM; const bf16* Bw;
    float* C; const float* bias; float* PART;
    int Mtot, ldc, Nvalid, sigfrom;
    int Ho, Wo, Hi, Wi, Wm, HmWm, stride, osub, blk0, Pin;
};
struct FD7 { FD d[7]; int n; };
struct SD { const float* part; const float* gamma; const float* beta;
            float* stats; float* gapn; int nblk, HW; };
struct SD7 { SD d[7]; };
struct WD { const float* Fs; float* partw; int Hh, Wh, Hm, Wm; };
struct WD2 { WD d[2]; };
struct AD { const float* gapn; const float* partw; const float* statsH; float invHW; int nbr; };
struct AD3 { AD d[3]; };
struct CD { const float* f0; const float* f1; const float* Fs;
            const float* stats; const float* abr; const float* dyc; float* outp;
            int H, W, nbr, Hh, Wh, slotH, blk0; };
struct CD3 { CD d[3]; };

// ================= batched weight conversion =================
__global__ __launch_bounds__(256) void k_convwB(VD4 P){
    int bx = blockIdx.x;
    VD dd = P.d[0];
    #pragma unroll
    for (int i = 1; i < 4; ++i) if (bx >= P.d[i].blk0) dd = P.d[i];
    int i = (bx - dd.blk0)*256 + threadIdx.x;
    if (i >= dd.Opad*2304) return;
    int o = i / 2304, r = i - o*2304;
    int k = r >> 8, c = r & 255;
    float v = 0.f;
    if (o < dd.Ovalid) v = dd.w[((size_t)(o*256 + c))*9 + k];
    dd.bw[i] = __float2bfloat16(v);
}

// ================= batched X fp32 NCHW -> bf16 chunk-major [32][Ptot][8] =================
__global__ __launch_bounds__(256) void k_xconvB(XD3 P){
    __shared__ bf16 T[64][264];
    int bx = blockIdx.x;
    XD dd = P.d[0];
    #pragma unroll
    for (int i = 1; i < 3; ++i) if (bx >= P.d[i].blk0) dd = P.d[i];
    int HW = dd.HW, Ptot = dd.Ptot;
    int t = threadIdx.x;
    int pbase = (bx - dd.blk0)*64;
    int px = t & 63, cg = t >> 6;
    int p = pbase + px;
    if (p < Ptot){
        int b = p / HW, rem = p - b*HW;
        const float* xb = dd.X + (size_t)b*256*HW + rem;
        for (int c = cg; c < 256; c += 4)
            T[px][c] = __float2bfloat16(xb[(size_t)c*HW]);
    }
    __syncthreads();
    for (int jj = 0; jj < 8; ++jj){
        int ck = jj*4 + (t >> 6);
        int opx = t & 63;
        int op = pbase + opx;
        if (op < Ptot){
            uint4 u = *(const uint4*)&T[opx][ck << 3];
            *(uint4*)&dd.O[((size_t)ck*Ptot + op)*8] = u;
        }
    }
}

// ======== shared meta phase (emitted inline in both conv kernels via macro) ========
#define META_PHASE() \
    for (int i = t; i < 576; i += 512){ \
        int p_ = i & 63, k = i >> 6; \
        int p = m0 + p_; \
        bool pv = p < Mtot; \
        int pp = pv ? p : 0; \
        int b = pp / HoWo; int r = pp - b*HoWo; int y = r / Wo; int x = r - y*Wo; \
        float offy = 0.f, offx = 0.f, mk = 1.f; \
        if (OM){ \
            size_t ob = ((size_t)b*HmWm + (size_t)(y*osub)*Wm + (size_t)(x*osub)) * 32; \
            offy = OM[ob + 2*k]; offx = OM[ob + 2*k + 1]; mk = OM[ob + 18 + k]; \
        } \
        if (!pv) mk = 0.f; \
        int kh = k/3, kw = k - kh*3; \
        float py = (float)(y*stride - 1 + kh) + offy; \
        float pxf = (float)(x*stride - 1 + kw) + offx; \
        float y0f = floorf(py), x0f = floorf(pxf); \
        float ly = py - y0f, lx = pxf - x0f; \
        int y0 = (int)y0f, x0 = (int)x0f; \
        int y1 = y0 + 1, x1 = x0 + 1; \
        float vy0 = (y0 >= 0 && y0 < Hi) ? 1.f : 0.f; \
        float vy1 = (y1 >= 0 && y1 < Hi) ? 1.f : 0.f; \
        float vx0 = (x0 >= 0 && x0 < Wi) ? 1.f : 0.f; \
        float vx1 = (x1 >= 0 && x1 < Wi) ? 1.f : 0.f; \
        int y0c = min(max(y0,0),Hi-1), y1c = min(max(y1,0),Hi-1); \
        int x0c = min(max(x0,0),Wi-1), x1c = min(max(x1,0),Wi-1); \
        int base = b*HiWi; \
        smi[(k*64+p_)*4+0] = base + y0c*Wi + x0c; \
        smi[(k*64+p_)*4+1] = base + y0c*Wi + x1c; \
        smi[(k*64+p_)*4+2] = base + y1c*Wi + x0c; \
        smi[(k*64+p_)*4+3] = base + y1c*Wi + x1c; \
        smw[(k*64+p_)*4+0] = (1.f-ly)*(1.f-lx)*mk*vy0*vx0; \
        smw[(k*64+p_)*4+1] = (1.f-ly)*lx*mk*vy0*vx1; \
        smw[(k*64+p_)*4+2] = ly*(1.f-lx)*mk*vy1*vx0; \
        smw[(k*64+p_)*4+3] = ly*lx*mk*vy1*vx1; \
    }

// ================= branch conv: bilinear gather + 64x256 GEMM + GN partials =================
// 512 thr, 8 waves (2x4). Named registers only — no arrays, no lambdas (scratch-spill fix).
__global__ __launch_bounds__(512, 1) void k_convBrB(FD7 P){
    __shared__ __align__(16) char smem[(64*64 + 256*64)*2 + 9*64*32];
    bf16* sA = (bf16*)smem;
    bf16* sB = sA + 64*64;
    int*  smi = (int*)(smem + (size_t)(64*64 + 256*64)*2);
    float* smw = (float*)(smi + 9*64*4);
    float* sP = (float*)smem;

    int bx = blockIdx.x;
    FD dd = P.d[0];
    #pragma unroll
    for (int i = 1; i < 7; ++i) if (i < P.n && bx >= P.d[i].blk0) dd = P.d[i];
    const bf16* __restrict__ X16 = dd.X16;
    const float* __restrict__ OM = dd.OM;
    const bf16* __restrict__ Bw  = dd.Bw;
    float* __restrict__ C        = dd.C;
    float* __restrict__ PART     = dd.PART;
    const int Mtot = dd.Mtot;
    const int Ho = dd.Ho, Wo = dd.Wo, Hi = dd.Hi, Wi = dd.Wi;
    const int Wm = dd.Wm, HmWm = dd.HmWm, stride = dd.stride, osub = dd.osub;
    const size_t Pin8 = (size_t)dd.Pin * 8;

    const int t = threadIdx.x;
    const int m0 = (bx - dd.blk0) * 64;
    const int HoWo = Ho * Wo;
    const int HiWi = Hi * Wi;
    const int px = t & 63;
    const int cg = t >> 6;

    META_PHASE();
    __syncthreads();

    frag_cd zero = {0.f,0.f,0.f,0.f};
    frag_cd a00 = zero, a01 = zero, a02 = zero, a03 = zero;
    frag_cd a10 = zero, a11 = zero, a12 = zero, a13 = zero;

    const int l = t & 63;
    const int wr = cg >> 2, wc = cg & 3;
    const int lr = l & 15, lq = l >> 4;
    const int lk8 = lq * 8;
    const int r0 = t >> 3;
    const int c8x = ((t & 7) << 3) ^ ((r0 & 7) << 3);

    uint4 xA0, xA1, xA2, xA3, bA0, bA1, bA2, bA3;
    float4 cw;

#define LOADG(KT) do{ \
        int k_ = (KT) >> 2; \
        const bf16* Xc_ = X16 + (size_t)(((KT) & 3)*8 + cg) * Pin8; \
        int4 ci_ = *(const int4*)&smi[(k_*64+px)*4]; \
        cw = *(const float4*)&smw[(k_*64+px)*4]; \
        xA0 = *(const uint4*)&Xc_[(size_t)ci_.x * 8]; \
        xA1 = *(const uint4*)&Xc_[(size_t)ci_.y * 8]; \
        xA2 = *(const uint4*)&Xc_[(size_t)ci_.z * 8]; \
        xA3 = *(const uint4*)&Xc_[(size_t)ci_.w * 8]; \
        const bf16* Bb_ = Bw + (size_t)(KT)*64 + ((t & 7) << 3); \
        bA0 = *(const uint4*)&Bb_[(size_t)(r0      )*2304]; \
        bA1 = *(const uint4*)&Bb_[(size_t)(r0 +  64)*2304]; \
        bA2 = *(const uint4*)&Bb_[(size_t)(r0 + 128)*2304]; \
        bA3 = *(const uint4*)&Bb_[(size_t)(r0 + 192)*2304]; \
    } while(0)

    LOADG(0);
    for (int kt = 0; kt < 36; ++kt){
        uint4 pk;
        pk.x = mix4(cw, xA0.x, xA1.x, xA2.x, xA3.x);
        pk.y = mix4(cw, xA0.y, xA1.y, xA2.y, xA3.y);
        pk.z = mix4(cw, xA0.z, xA1.z, xA2.z, xA3.z);
        pk.w = mix4(cw, xA0.w, xA1.w, xA2.w, xA3.w);
        __syncthreads();
        *(uint4*)&sA[px*64 + ((cg*8) ^ ((px & 7) << 3))] = pk;
        *(uint4*)&sB[(r0      )*64 + c8x] = bA0;
        *(uint4*)&sB[(r0 +  64)*64 + c8x] = bA1;
        *(uint4*)&sB[(r0 + 128)*64 + c8x] = bA2;
        *(uint4*)&sB[(r0 + 192)*64 + c8x] = bA3;
        __syncthreads();
        if (kt < 35) LOADG(kt + 1);
        const int sz = (lr & 7) << 3;
        #pragma unroll
        for (int kk = 0; kk < 2; ++kk){
            int colx = (kk*32 + lk8) ^ sz;
            frag_ab av0 = *(const frag_ab*)&sA[(wr*32 +      lr)*64 + colx];
            frag_ab av1 = *(const frag_ab*)&sA[(wr*32 + 16 + lr)*64 + colx];
            frag_ab bv0 = *(const frag_ab*)&sB[(wc*64 +      lr)*64 + colx];
            frag_ab bv1 = *(const frag_ab*)&sB[(wc*64 + 16 + lr)*64 + colx];
            frag_ab bv2 = *(const frag_ab*)&sB[(wc*64 + 32 + lr)*64 + colx];
            frag_ab bv3 = *(const frag_ab*)&sB[(wc*64 + 48 + lr)*64 + colx];
            a00 = __builtin_amdgcn_mfma_f32_16x16x32_bf16(av0, bv0, a00, 0, 0, 0);
            a01 = __builtin_amdgcn_mfma_f32_16x16x32_bf16(av0, bv1, a01, 0, 0, 0);
            a02 = __builtin_amdgcn_mfma_f32_16x16x32_bf16(av0, bv2, a02, 0, 0, 0);
            a03 = __builtin_amdgcn_mfma_f32_16x16x32_bf16(av0, bv3, a03, 0, 0, 0);
            a10 = __builtin_amdgcn_mfma_f32_16x16x32_bf16(av1, bv0, a10, 0, 0, 0);
            a11 = __builtin_amdgcn_mfma_f32_16x16x32_bf16(av1, bv1, a11, 0, 0, 0);
            a12 = __builtin_amdgcn_mfma_f32_16x16x32_bf16(av1, bv2, a12, 0, 0, 0);
            a13 = __builtin_amdgcn_mfma_f32_16x16x32_bf16(av1, bv3, a13, 0, 0, 0);
        }
    }
#undef LOADG

    // ---- C write (ldc=256, no bias/sigmoid on branch path) ----
    {
        int gr0 = m0 + wr*32 + lq*4;
        int gc  = wc*64 + lr;
        cwrite4(C, Mtot, gr0,      gc,      a00);
        cwrite4(C, Mtot, gr0,      gc + 16, a01);
        cwrite4(C, Mtot, gr0,      gc + 32, a02);
        cwrite4(C, Mtot, gr0,      gc + 48, a03);
        cwrite4(C, Mtot, gr0 + 16, gc,      a10);
        cwrite4(C, Mtot, gr0 + 16, gc + 16, a11);
        cwrite4(C, Mtot, gr0 + 16, gc + 32, a12);
        cwrite4(C, Mtot, gr0 + 16, gc + 48, a13);
    }

    // ---- GN partial sums ----
    __syncthreads();
    {
        const int b0 = m0 / HoWo;
        const int bsplit = (b0 + 1) * HoWo;
        int gr0 = m0 + wr*32 + lq*4;
        int gcl = wc*64 + lr;
        int slot = wr*4 + lq;
        float4 z4 = {0.f,0.f,0.f,0.f};
        float4 s0 = statacc(statacc(z4, gr0, Mtot, bsplit, a00), gr0+16, Mtot, bsplit, a10);
        float4 s1 = statacc(statacc(z4, gr0, Mtot, bsplit, a01), gr0+16, Mtot, bsplit, a11);
        float4 s2 = statacc(statacc(z4, gr0, Mtot, bsplit, a02), gr0+16, Mtot, bsplit, a12);
        float4 s3 = statacc(statacc(z4, gr0, Mtot, bsplit, a03), gr0+16, Mtot, bsplit, a13);
        *(float4*)&sP[((slot*256) + gcl     )*4] = s0;
        *(float4*)&sP[((slot*256) + gcl + 16)*4] = s1;
        *(float4*)&sP[((slot*256) + gcl + 32)*4] = s2;
        *(float4*)&sP[((slot*256) + gcl + 48)*4] = s3;
    }
    __syncthreads();
    if (t < 256){
        float4 s = {0.f,0.f,0.f,0.f};
        #pragma unroll
        for (int sl = 0; sl < 8; ++sl){
            float4 v = *(const float4*)&sP[((sl*256)+t)*4];
            s.x += v.x; s.y += v.y; s.z += v.z; s.w += v.w;
        }
        *(float4*)&PART[((size_t)(bx - dd.blk0)*256 + t)*4] = s;
    }
}

// ================= offset conv: plain im2col + 64x64 GEMM (bias + sigmoid cols>=18) =============
__global__ __launch_bounds__(512, 1) void k_convOffB(FD7 P){
    __shared__ __align__(16) char smem[(64*64 + 64*64)*2 + 9*64*32];
    bf16* sA = (bf16*)smem;
    bf16* sB = sA + 64*64;
    int*  smi = (int*)(smem + (size_t)(64*64 + 64*64)*2);
    float* smw = (float*)(smi + 9*64*4);

    int bx = blockIdx.x;
    FD dd = P.d[0];
    #pragma unroll
    for (int i = 1; i < 3; ++i) if (bx >= P.d[i].blk0) dd = P.d[i];
    const bf16* __restrict__ X16 = dd.X16;
    const float* OM = nullptr;
    const bf16* __restrict__ Bw  = dd.Bw;
    float* __restrict__ C        = dd.C;
    const float* __restrict__ bias = dd.bias;
    const int Mtot = dd.Mtot;
    const int Ho = dd.Ho, Wo = dd.Wo, Hi = dd.Hi, Wi = dd.Wi;
    const int Wm = dd.Wm, HmWm = dd.HmWm, stride = dd.stride, osub = dd.osub;
    const size_t Pin8 = (size_t)dd.Pin * 8;

    const int t = threadIdx.x;
    const int m0 = (bx - dd.blk0) * 64;
    const int HoWo = Ho * Wo;
    const int HiWi = Hi * Wi;
    const int px = t & 63;
    const int cg = t >> 6;

    META_PHASE();
    __syncthreads();

    frag_cd zero = {0.f,0.f,0.f,0.f};
    frag_cd a00 = zero, a10 = zero;

    const int l = t & 63;
    const int wr = cg >> 2, wc = cg & 3;
    const int lr = l & 15, lq = l >> 4;
    const int lk8 = lq * 8;
    const int r0 = t >> 3;
    const int c8x = ((t & 7) << 3) ^ ((r0 & 7) << 3);

    uint4 xA0, bA0;
    float cwx;

#define LOADG(KT) do{ \
        int k_ = (KT) >> 2; \
        const bf16* Xc_ = X16 + (size_t)(((KT) & 3)*8 + cg) * Pin8; \
        int ci_ = smi[(k_*64+px)*4]; \
        cwx = smw[(k_*64+px)*4]; \
        xA0 = *(const uint4*)&Xc_[(size_t)ci_ * 8]; \
        bA0 = *(const uint4*)&Bw[(size_t)r0*2304 + (size_t)(KT)*64 + ((t & 7) << 3)]; \
    } while(0)

    LOADG(0);
    for (int kt = 0; kt < 36; ++kt){
        uint4 z = {0u,0u,0u,0u};
        uint4 pk = (cwx > 0.5f) ? xA0 : z;
        __syncthreads();
        *(uint4*)&sA[px*64 + ((cg*8) ^ ((px & 7) << 3))] = pk;
        *(uint4*)&sB[r0*64 + c8x] = bA0;
        __syncthreads();
        if (kt < 35) LOADG(kt + 1);
        const int sz = (lr & 7) << 3;
        #pragma unroll
        for (int kk = 0; kk < 2; ++kk){
            int colx = (kk*32 + lk8) ^ sz;
            frag_ab av0 = *(const frag_ab*)&sA[(wr*32 +      lr)*64 + colx];
            frag_ab av1 = *(const frag_ab*)&sA[(wr*32 + 16 + lr)*64 + colx];
            frag_ab bv0 = *(const frag_ab*)&sB[(wc*16 +      lr)*64 + colx];
            a00 = __builtin_amdgcn_mfma_f32_16x16x32_bf16(av0, bv0, a00, 0, 0, 0);
            a10 = __builtin_amdgcn_mfma_f32_16x16x32_bf16(av1, bv0, a10, 0, 0, 0);
        }
    }
#undef LOADG

    int gc = wc*16 + lr;
    if (gc < 27){
        float bv_ = bias[gc];
        #pragma unroll
        for (int jj = 0; jj < 4; ++jj){
            int r = m0 + wr*32 + lq*4 + jj;
            if (r < Mtot){
                float v = a00[jj] + bv_;
                if (gc >= 18) v = 1.f / (1.f + expf(-v));
                C[(size_t)r*32 + gc] = v;
            }
            int r2 = r + 16;
            if (r2 < Mtot){
                float v = a10[jj] + bv_;
                if (gc >= 18) v = 1.f / (1.f + expf(-v));
                C[(size_t)r2*32 + gc] = v;
            }
        }
    }
}

// ================= batched GN stats + normalized GAP =================
__global__ __launch_bounds__(256) void k_statsB(SD7 P, int njob){
    int job = blockIdx.y;
    if (job >= njob) return;
    SD dd = P.d[0];
    #pragma unroll
    for (int i = 1; i < 7; ++i) if (i == job) dd = P.d[i];
    int nblk = dd.nblk, HW = dd.HW;
    int b = blockIdx.x, t = threadIdx.x;
    float s1 = 0.f, s2 = 0.f;
    for (int blk = 0; blk < nblk; ++blk){
        int b0 = (blk*64) / HW;
        float4 v = *(const float4*)&dd.part[((size_t)blk*256 + t)*4];
        if (b0 == b)     { s1 += v.x; s2 += v.y; }
        if (b0 + 1 == b) { s1 += v.z; s2 += v.w; }
    }
    float invHW = 1.0f / (float)HW;
    float g1 = s1, g2 = s2;
    #pragma unroll
    for (int m = 8; m >= 1; m >>= 1){ g1 += __shfl_xor(g1, m, 16); g2 += __shfl_xor(g2, m, 16); }
    float mu  = g1 * invHW * (1.f/16.f);
    float var = g2 * invHW * (1.f/16.f) - mu*mu;
    float rstd = rsqrtf(var + 1e-5f);
    if ((t & 15) == 0){ int g = t >> 4; dd.stats[(b*16+g)*2] = mu; dd.stats[(b*16+g)*2+1] = rstd; }
    dd.gapn[b*256 + t] = (s1*invHW - mu)*rstd*dd.gamma[t] + dd.beta[t];
}

// ================= batched weighted partials for resized-high GAP =================
__global__ __launch_bounds__(256) void k_wredB(WD2 P, int nlev){
    int lev = blockIdx.z;
    if (lev >= nlev) return;
    WD dd = P.d[0];
    #pragma unroll
    for (int i = 1; i < 2; ++i) if (i == lev) dd = P.d[i];
    int Hh = dd.Hh, Wh = dd.Wh, Hm = dd.Hm, Wm = dd.Wm;
    __shared__ float wy[80], wx[80];
    int t = threadIdx.x;
    int b = blockIdx.y, ch = blockIdx.x;
    if (t < Hh){
        float s = 0.f;
        for (int oy = 0; oy < Hm; ++oy){
            float ry = (float)(oy*(Hh-1)) / (float)(Hm-1);
            int y0 = (int)ry; float f = ry - (float)y0; int y1 = min(y0+1, Hh-1);
            if (y0 == t) s += 1.f - f;
            if (y1 == t) s += f;
        }
        wy[t] = s;
    }
    if (t < Wh){
        float s = 0.f;
        for (int ox = 0; ox < Wm; ++ox){
            float rx = (float)(ox*(Wh-1)) / (float)(Wm-1);
            int x0 = (int)rx; float f = rx - (float)x0; int x1 = min(x0+1, Wh-1);
            if (x0 == t) s += 1.f - f;
            if (x1 == t) s += f;
        }
        wx[t] = s;
    }
    __syncthreads();
    int HWh = Hh*Wh;
    int R = (HWh + 15) / 16;
    int rb = ch*R, re = min(rb + R, HWh);
    float s = 0.f;
    for (int r = rb; r < re; ++r){
        int y = r / Wh, x = r - y*Wh;
        s += wy[y]*wx[x] * dd.Fs[((size_t)b*HWh + r)*256 + t];
    }
    dd.partw[((size_t)(b*16 + ch))*256 + t] = s;
}

// ================= batched attention + dyrelu coefficients =================
__global__ __launch_bounds__(256) void k_attnB(AD3 P,
    const float* __restrict__ gH, const float* __restrict__ bH,
    const float* __restrict__ sw, const float* __restrict__ sb,
    const float* __restrict__ w1, const float* __restrict__ b1v,
    const float* __restrict__ w2, const float* __restrict__ b2v,
    float* __restrict__ ABR, float* __restrict__ DYC)
{
    int lev = blockIdx.y;
    AD dd = P.d[0];
    #pragma unroll
    for (int i = 1; i < 3; ++i) if (i == lev) dd = P.d[i];
    int nbr = dd.nbr;
    float* abr = ABR + lev*8;
    float* dyc = DYC + (size_t)lev*2048;
    int b = blockIdx.x, t = threadIdx.x;
    const int B = 2;
    __shared__ float gbuf[3][256];
    __shared__ float red[256];
    __shared__ float asl[3];
    __shared__ float hh[64];
    for (int br = 0; br < nbr; ++br){
        float g;
        if (dd.partw && br == nbr-1){
            g = 0.f;
            for (int i = 0; i < 16; ++i) g += dd.partw[((size_t)(b*16 + i))*256 + t];
            int gi = t >> 4;
            float mu = dd.statsH[(b*16+gi)*2], rs = dd.statsH[(b*16+gi)*2+1];
            g = (g*dd.invHW - mu)*rs*gH[t] + bH[t];
        } else {
            g = dd.gapn[((size_t)br*B + b)*256 + t];
        }
        gbuf[br][t] = g;
    }
    __syncthreads();
    for (int br = 0; br < nbr; ++br){
        red[t] = gbuf[br][t] * sw[t];
        __syncthreads();
        for (int s = 128; s > 0; s >>= 1){ if (t < s) red[t] += red[t+s]; __syncthreads(); }
        if (t == 0) asl[br] = hsig(fmaxf(red[0] + sb[0], 0.f));
        __syncthreads();
    }
    float gmv = 0.f;
    for (int br = 0; br < nbr; ++br) gmv += asl[br]*gbuf[br][t];
    gmv /= (float)nbr;
    red[t] = gmv;
    __syncthreads();
    if (t < 64){
        float h = b1v[t];
        for (int c = 0; c < 256; ++c) h += w1[t*256 + c]*red[c];
        hh[t] = fmaxf(h, 0.f);
    }
    __syncthreads();
    float co0, co1, co2, co3;
    {
        float s0 = b2v[t], s1 = b2v[256 + t], s2 = b2v[512 + t], s3 = b2v[768 + t];
        for (int kk = 0; kk < 64; ++kk){
            float hv = hh[kk];
            s0 += w2[(t      )*64 + kk]*hv;
            s1 += w2[(256 + t)*64 + kk]*hv;
            s2 += w2[(512 + t)*64 + kk]*hv;
            s3 += w2[(768 + t)*64 + kk]*hv;
        }
        co0 = hsig(s0); co1 = hsig(s1); co2 = hsig(s2); co3 = hsig(s3);
    }
    dyc[((size_t)b*256 + t)*4 + 0] = (co0 - 0.5f)*2.f + 1.f;
    dyc[((size_t)b*256 + t)*4 + 1] =  co1 - 0.5f;
    dyc[((size_t)b*256 + t)*4 + 2] = (co2 - 0.5f)*2.f;
    dyc[((size_t)b*256 + t)*4 + 3] =  co3 - 0.5f;
    if (t < nbr) abr[b*3 + t] = asl[t];
}

// ================= batched combine (+inline high resize) + dyrelu, NHWC -> NCHW ================
__global__ __launch_bounds__(256) void k_combineB(CD3 P,
    const float* __restrict__ g0v, const float* __restrict__ b0v,
    const float* __restrict__ glv, const float* __restrict__ blv,
    const float* __restrict__ ghv, const float* __restrict__ bhv)
{
    __shared__ float TL[256*17];
    int bid = blockIdx.x;
    CD dd = P.d[0];
    #pragma unroll
    for (int i = 1; i < 3; ++i) if (bid >= P.d[i].blk0) dd = P.d[i];
    const float* f0 = dd.f0;
    const float* f1 = dd.f1;
    const float* Fs = dd.Fs;
    const float* stats = dd.stats;
    const float* abr = dd.abr;
    const float* dyc = dd.dyc;
    float* outp = dd.outp;
    int H = dd.H, W = dd.W, nbr = dd.nbr;
    int Hh = dd.Hh, Wh = dd.Wh, slotH = dd.slotH;
    bid -= dd.blk0;

    int t = threadIdx.x;
    int nchx = (W + 15) >> 4;
    int cx = bid % nchx; int rem = bid / nchx;
    int y = rem % H; int b = rem / H;
    float a0 = abr[b*3 + 0];
    float alow = f1 ? abr[b*3 + 1] : 0.f;
    float ahigh = Fs ? abr[b*3 + (nbr-1)] : 0.f;
    float inv = 1.f / (float)nbr;
    int g = t >> 4;
    float mu0 = stats[b*32 + g*2], rs0 = stats[b*32 + g*2 + 1];
    float mu1 = 0.f, rs1 = 0.f, muh = 0.f, rsh = 0.f;
    if (f1){ mu1 = stats[64 + b*32 + g*2]; rs1 = stats[64 + b*32 + g*2 + 1]; }
    if (Fs){ muh = stats[slotH*64 + b*32 + g*2]; rsh = stats[slotH*64 + b*32 + g*2 + 1]; }
    float dcx = dyc[((size_t)b*256 + t)*4 + 0];
    float dcy = dyc[((size_t)b*256 + t)*4 + 1];
    float dcz = dyc[((size_t)b*256 + t)*4 + 2];
    float dcw = dyc[((size_t)b*256 + t)*4 + 3];
    size_t HW = (size_t)H*W;
    int y0 = 0, y1 = 0; float fy = 0.f;
    if (Fs){
        float ry = (float)(y*(Hh-1)) / (float)(H-1);
        y0 = (int)ry; fy = ry - (float)y0; y1 = min(y0+1, Hh-1);
    }
    for (int i = 0; i < 16; ++i){
        int x = (cx << 4) + i;
        if (x < W){
            size_t row = (size_t)b*HW + (size_t)y*W + x;
            float v = a0 * ((f0[row*256 + t] - mu0)*rs0*g0v[t] + b0v[t]);
            if (f1) v += alow * ((f1[row*256 + t] - mu1)*rs1*glv[t] + blv[t]);
            if (Fs){
                float rx = (float)(x*(Wh-1)) / (float)(W-1);
                int x0 = (int)rx; float fx = rx - (float)x0; int x1 = min(x0+1, Wh-1);
                size_t basep = (size_t)b*Hh*Wh;
                float v00 = Fs[(basep + (size_t)y0*Wh + x0)*256 + t];
                float v01 = Fs[(basep + (size_t)y0*Wh + x1)*256 + t];
                float v10 = Fs[(basep + (size_t)y1*Wh + x0)*256 + t];
                float v11 = Fs[(basep + (size_t)y1*Wh + x1)*256 + t];
                float vi = (1.f-fy)*((1.f-fx)*v00 + fx*v01) + fy*((1.f-fx)*v10 + fx*v11);
                v += ahigh * ((vi - muh)*rsh*ghv[t] + bhv[t]);
            }
            v *= inv;
            TL[t*17 + i] = fmaxf(v*dcx + dcy, v*dcz + dcw);
        }
    }
    __syncthreads();
    int px = t & 15, cwi = t >> 4;
    for (int cb = 0; cb < 16; ++cb){
        int c = cb*16 + cwi;
        int x = (cx << 4) + px;
        if (x < W) outp[((size_t)(b*256 + c)*H + y)*W + x] = TL[c*17 + px];
    }
}

extern "C" void kernel_launch(void* const* d_in, const int* in_sizes, int n_in,
                              void* d_out, int out_size, void* d_ws, size_t ws_size,
                              hipStream_t stream)
{
    (void)in_sizes; (void)n_in; (void)out_size; (void)ws_size;
    const float* X[3]   = {(const float*)d_in[0], (const float*)d_in[1], (const float*)d_in[2]};
    const float* off_w  = (const float*)d_in[3];
    const float* off_b  = (const float*)d_in[4];
    const float* wbr[3] = {(const float*)d_in[5], (const float*)d_in[8], (const float*)d_in[11]};
    const float* gbr[3] = {(const float*)d_in[6], (const float*)d_in[9], (const float*)d_in[12]};
    const float* bbr[3] = {(const float*)d_in[7], (const float*)d_in[10], (const float*)d_in[13]};
    const float* sw  = (const float*)d_in[14];
    const float* sb  = (const float*)d_in[15];
    const float* d1w = (const float*)d_in[16];
    const float* d1b = (const float*)d_in[17];
    const float* d2w = (const float*)d_in[18];
    const float* d2b = (const float*)d_in[19];

    const int Hs[3] = {80, 40, 20};
    const int HWs[3] = {6400, 1600, 400};
    uint8_t* base = (uint8_t*)d_ws;
    size_t off = 0;
    auto alloc = [&](size_t bytes)->void*{
        off = (off + 255) & ~(size_t)255;
        void* p = base + off; off += bytes; return p;
    };
    bf16* BWO = (bf16*)alloc((size_t)64*2304*2);
    bf16* BWB[3];
    for (int i = 0; i < 3; ++i) BWB[i] = (bf16*)alloc((size_t)256*2304*2);
    bf16* X16[3];
    for (int L = 0; L < 3; ++L) X16[L] = (bf16*)alloc((size_t)2*HWs[L]*256*2);
    float* OMl[3];
    for (int L = 0; L < 3; ++L) OMl[L] = (float*)alloc((size_t)2*HWs[L]*32*4);
    float* Fm[3]; float* Fl[3]; float* Fh[3];
    for (int L = 0; L < 3; ++L) Fm[L] = (float*)alloc((size_t)2*HWs[L]*256*4);
    for (int L = 1; L < 3; ++L) Fl[L] = (float*)alloc((size_t)2*HWs[L]*256*4);
    Fl[0] = nullptr;
    for (int L = 0; L < 2; ++L) Fh[L] = (float*)alloc((size_t)2*HWs[L+1]*256*4);
    Fh[2] = nullptr;
    float* GAPN[3]; float* STATS[3];
    for (int L = 0; L < 3; ++L){
        GAPN[L]  = (float*)alloc((size_t)3*2*256*4);
        STATS[L] = (float*)alloc((size_t)3*64*4);
    }
    float* PARTW[2];
    for (int L = 0; L < 2; ++L) PARTW[L] = (float*)alloc((size_t)2*16*256*4);
    float* ABR = (float*)alloc((size_t)3*8*4);
    float* DYC = (float*)alloc((size_t)3*2048*4);

    // ---- weight conversion batch ----
    {
        VD4 P;
        int blk = 0;
        P.d[0] = {off_w, BWO, 64, 27, blk}; blk += ceildiv(64*2304, 256);
        for (int i = 0; i < 3; ++i){ P.d[1+i] = {wbr[i], BWB[i], 256, 256, blk}; blk += ceildiv(256*2304, 256); }
        k_convwB<<<blk,256,0,stream>>>(P);
    }
    // ---- X transpose batch (chunk-major output) ----
    {
        XD3 P;
        int blk = 0;
        for (int L = 0; L < 3; ++L){ P.d[L] = {X[L], X16[L], HWs[L], 2*HWs[L], blk}; blk += ceildiv(2*HWs[L], 64); }
        k_xconvB<<<blk,256,0,stream>>>(P);
    }
    const int BIG = 1 << 30;
    // ---- offset conv batch ----
    {
        FD7 P; P.n = 3;
        int blk = 0;
        for (int L = 0; L < 3; ++L){
            int H = Hs[L], HW = HWs[L], M = 2*HW;
            P.d[L] = {X16[L], nullptr, BWO, OMl[L], off_b, nullptr,
                      M, 32, 27, 18, H, H, H, H, H, HW, 1, 1, blk, M};
            blk += ceildiv(M, 64);
        }
        k_convOffB<<<blk,512,0,stream>>>(P);
    }
    // ---- branch conv batch ----
    FD7 BP; SD7 SP;
    int nbranch = 0, bblk = 0;
    auto addBranch = [&](int L, int type){
        int H = Hs[L], HW = HWs[L];
        int slot, Ho, Wo, Hi, Wi, stride, osub, Mtot, HWo;
        const bf16* xp; float* cp;
        bool has_low = (L > 0), has_high = (L < 2);
        int nbr = 1 + (has_low?1:0) + (has_high?1:0);
        if (type == 0){ slot = 0; Ho=H; Wo=H; Hi=H; Wi=H; stride=1; osub=1; xp=X16[L]; cp=Fm[L]; }
        else if (type == 1){ slot = 1; Ho=H; Wo=H; Hi=2*H; Wi=2*H; stride=2; osub=1; xp=X16[L-1]; cp=Fl[L]; }
        else { slot = nbr-1; Ho=H/2; Wo=H/2; Hi=H/2; Wi=H/2; stride=1; osub=2; xp=X16[L+1]; cp=Fh[L]; }
        HWo = Ho*Wo; Mtot = 2*HWo;
        int nblk = ceildiv(Mtot, 64);
        float* part = (float*)alloc((size_t)nblk*256*4*4);
        BP.d[nbranch] = {xp, OMl[L], BWB[type], cp, nullptr, part,
                         Mtot, 256, 256, BIG, Ho, Wo, Hi, Wi, H, HW, stride, osub, bblk, 2*Hi*Wi};
        SP.d[nbranch] = {part, gbr[type], bbr[type], STATS[L] + slot*64, GAPN[L] + slot*512, nblk, HWo};
        bblk += nblk; ++nbranch;
    };
    for (int L = 0; L < 3; ++L){
        addBranch(L, 0);
        if (L > 0) addBranch(L, 1);
        if (L < 2) addBranch(L, 2);
    }
    BP.n = nbranch;
    k_convBrB<<<bblk,512,0,stream>>>(BP);
    k_statsB<<<dim3(2,nbranch),256,0,stream>>>(SP, nbranch);
    // ---- wred batch ----
    {
        WD2 P;
        for (int L = 0; L < 2; ++L)
            P.d[L] = {Fh[L], PARTW[L], Hs[L]/2, Hs[L]/2, Hs[L], Hs[L]};
        k_wredB<<<dim3(16,2,2),256,0,stream>>>(P, 2);
    }
    // ---- attn batch ----
    {
        AD3 P;
        for (int L = 0; L < 3; ++L){
            bool has_low = (L > 0), has_high = (L < 2);
            int nbr = 1 + (has_low?1:0) + (has_high?1:0);
            int slotH = nbr - 1;
            P.d[L] = {GAPN[L], has_high ? PARTW[L] : nullptr, STATS[L] + slotH*64,
                      1.f/(float)HWs[L], nbr};
        }
        k_attnB<<<dim3(2,3),256,0,stream>>>(P, gbr[2], bbr[2], sw, sb, d1w, d1b, d2w, d2b, ABR, DYC);
    }
    // ---- combine batch ----
    {
        CD3 P;
        int blk = 0;
        size_t lvl_off = 0;
        for (int L = 0; L < 3; ++L){
            int H = Hs[L], W = Hs[L];
            bool has_low = (L > 0), has_high = (L < 2);
            int nbr = 1 + (has_low?1:0) + (has_high?1:0);
            P.d[L] = {Fm[L], has_low ? Fl[L] : nullptr, has_high ? Fh[L] : nullptr,
                      STATS[L], ABR + L*8, DYC + (size_t)L*2048,
                      (float*)d_out + lvl_off, H, W, nbr, H/2, W/2, nbr-1, blk};
            blk += 2*H*ceildiv(W,16);
            lvl_off += (size_t)2*H*W*256;
        }
        k_combineB<<<blk,256,0,stream>>>(P, gbr[0], bbr[0], gbr[1], bbr[1], gbr[2], gbr[2] ? bbr[2] : bbr[2]);
    }
}